// Round 10
// baseline (542.447 us; speedup 1.0000x reference)
//
#include <hip/hip_runtime.h>
#include <hip/hip_bf16.h>
#include <hip/hip_fp16.h>

#define N_Q 10000
#define D_MODEL 256
#define NH 8
#define PT 4
#define PP 4
#define PS 4
#define DFF 1024
#define NC 6
#define HF 24
#define WF 60
#define BH 100
#define BW 100
#define T_RAD 0.15f
#define S_RAD 0.12f

typedef __hip_bfloat16 bf16;
typedef __attribute__((ext_vector_type(8))) short short8;
typedef __attribute__((ext_vector_type(4))) float f32x4;

__device__ __forceinline__ float b2f(bf16 v) { return __bfloat162float(v); }
__device__ __forceinline__ bf16 f2b(float v) { return __float2bfloat16(v); }

__device__ __forceinline__ f32x4 mfma16(short8 a, short8 b, f32x4 c) {
    return __builtin_amdgcn_mfma_f32_16x16x32_bf16(a, b, c, 0, 0, 0);
}

// dtype-adaptive loads/stores; f: 0=f32, 1=bf16, 2=f16
__device__ __forceinline__ float load_any(const void* p, long i, int f) {
    if (f == 0) return ((const float*)p)[i];
    if (f == 1) return b2f(((const bf16*)p)[i]);
    return __half2float(((const __half*)p)[i]);
}
__device__ __forceinline__ void store_any(void* p, long i, int f, float v) {
    if (f == 0)      ((float*)p)[i] = v;
    else if (f == 1) ((bf16*)p)[i] = f2b(v);
    else             ((__half*)p)[i] = __float2half(v);
}

__device__ __forceinline__ unsigned pack2(float a, float b) {
    bf16 x = f2b(a), y = f2b(b);
    unsigned short ux = *(unsigned short*)&x, uy = *(unsigned short*)&y;
    return (unsigned)ux | ((unsigned)uy << 16);
}

// ---------------- dtype / mask-width detection (parallel) ----------------
__global__ __launch_bounds__(256) void detect_kernel(const void* __restrict__ ln1g,
                                                     const void* __restrict__ mask,
                                                     int* __restrict__ flags) {
    __shared__ int sh[6];
    int tid = threadIdx.x;
    if (tid < 6) sh[tid] = (tid == 0 || tid == 2 || tid == 4) ? 1 : 0;
    __syncthreads();
    const unsigned long long* m64 = (const unsigned long long*)mask;
    const unsigned int*       m32 = (const unsigned int*)mask;
    const unsigned short*     m16 = (const unsigned short*)mask;
    int lok8 = 1, lones8 = 0, lok4 = 1, lones4 = 0, lok2 = 1, lones2 = 0;
    for (int i = tid; i < 480; i += 256) {
        if (i < 120) {
            unsigned long long v = m64[i];
            if (v == 1ULL) lones8++; else if (v != 0ULL) lok8 = 0;
        }
        if (i < 240) {
            unsigned int v = m32[i];
            if (v == 1u || v == 0x3F800000u) lones4++; else if (v != 0u) lok4 = 0;
        }
        unsigned short v = m16[i];
        if (v == 1 || v == 0x3F80) lones2++; else if (v != 0) lok2 = 0;
    }
    atomicAnd(&sh[0], lok8); atomicAdd(&sh[1], lones8);
    atomicAnd(&sh[2], lok4); atomicAdd(&sh[3], lones4);
    atomicAnd(&sh[4], lok2); atomicAdd(&sh[5], lones2);
    __syncthreads();
    if (tid == 0) {
        unsigned short u0 = ((const unsigned short*)ln1g)[0];
        flags[0] = (u0 == 0x3F80) ? 1 : (u0 == 0x3C00 ? 2 : 0);
        int ms;
        if (sh[0] && sh[1] > 30)       ms = 8;
        else if (sh[2] && sh[3] > 60)  ms = 4;
        else if (sh[4] && sh[5] > 120) ms = 2;
        else                           ms = 1;
        flags[1] = ms;
    }
}

// ---------------- unified weight/image prep: transposes + flat cvt + img transpose ----------------
#define NP 23
struct PrepDesc {
    const void* src[NP];
    int dst_off[NP];
    int count[NP];
    int R[NP];
    int C[NP];
    int type[NP];       // 0 flat cvt, 1 transpose, 2 img transpose
    int blk_start[NP + 1];
};
__global__ __launch_bounds__(256) void prep_kernel(PrepDesc pd, bf16* __restrict__ wgt,
                                                   bf16* __restrict__ imgT,
                                                   const int* __restrict__ flags) {
    int blk = blockIdx.x;
    int a = 0;
    while (a < NP - 1 && blk >= pd.blk_start[a + 1]) a++;
    int i = (blk - pd.blk_start[a]) * 256 + threadIdx.x;
    if (i >= pd.count[a]) return;
    int f = flags[0];
    int ty = pd.type[a];
    if (ty == 0) {
        wgt[pd.dst_off[a] + i] = f2b(load_any(pd.src[a], i, f));
    } else if (ty == 1) {
        int R = pd.R[a], C = pd.C[a];
        int c = i / R, r = i % R;
        wgt[pd.dst_off[a] + i] = f2b(load_any(pd.src[a], (long)r * C + c, f));
    } else {
        int ch = i & 255;
        int t = i >> 8;
        int xx = t % WF; t /= WF;
        int yy = t % HF;
        int c  = t / HF;
        long src = (((long)(c * 256) + ch) * HF + yy) * WF + xx;
        imgT[i] = f2b(load_any(pd.src[a], src, f));
    }
}

// ---------------- LN1 over prev_bev & query, wave-per-row -> ai[N,512] ----------------
__global__ __launch_bounds__(256) void ln12_kernel(const void* __restrict__ pb,
                                                   const void* __restrict__ q,
                                                   const int* __restrict__ flags,
                                                   const bf16* __restrict__ g,
                                                   const bf16* __restrict__ b,
                                                   bf16* __restrict__ out) {
    int wv = threadIdx.x >> 6, lane = threadIdx.x & 63;
    long row = (long)blockIdx.x * 4 + wv;
    const void* src; long r; int ooff;
    if (row < N_Q) { src = pb; r = row; ooff = 0; }
    else           { src = q;  r = row - N_Q; ooff = 256; }
    int f = flags[0];
    float v0, v1, v2, v3;
    if (f == 0) {
        float4 t = ((const float4*)src)[r * 64 + lane];
        v0 = t.x; v1 = t.y; v2 = t.z; v3 = t.w;
    } else {
        uint2 t = ((const uint2*)src)[r * 64 + lane];
        if (f == 1) {
            v0 = __uint_as_float(t.x << 16); v1 = __uint_as_float(t.x & 0xFFFF0000u);
            v2 = __uint_as_float(t.y << 16); v3 = __uint_as_float(t.y & 0xFFFF0000u);
        } else {
            __half2 h0 = *(__half2*)&t.x, h1 = *(__half2*)&t.y;
            v0 = __half2float(h0.x); v1 = __half2float(h0.y);
            v2 = __half2float(h1.x); v3 = __half2float(h1.y);
        }
    }
    float s1 = v0 + v1 + v2 + v3;
    float s2 = v0 * v0 + v1 * v1 + v2 * v2 + v3 * v3;
    #pragma unroll
    for (int m = 32; m > 0; m >>= 1) {
        s1 += __shfl_xor(s1, m);
        s2 += __shfl_xor(s2, m);
    }
    float mu = s1 * (1.f / 256.f);
    float var = s2 * (1.f / 256.f) - mu * mu;
    float inv = rsqrtf(var + 1e-5f);
    int k = lane * 4;
    float o0 = (v0 - mu) * inv * b2f(g[k+0]) + b2f(b[k+0]);
    float o1 = (v1 - mu) * inv * b2f(g[k+1]) + b2f(b[k+1]);
    float o2 = (v2 - mu) * inv * b2f(g[k+2]) + b2f(b[k+2]);
    float o3 = (v3 - mu) * inv * b2f(g[k+3]) + b2f(b[k+3]);
    uint2 st = {pack2(o0, o1), pack2(o2, o3)};
    *reinterpret_cast<uint2*>(out + r * 512 + ooff + k) = st;
}

// ---------------- LayerNorm (f32 in), wave-per-row -> bf16 out ----------------
__global__ __launch_bounds__(256) void ln_kernel(const float* __restrict__ in,
                                                 const bf16* __restrict__ g,
                                                 const bf16* __restrict__ b,
                                                 bf16* __restrict__ out) {
    int wv = threadIdx.x >> 6, lane = threadIdx.x & 63;
    long r = (long)blockIdx.x * 4 + wv;
    float4 t = ((const float4*)in)[r * 64 + lane];
    float s1 = t.x + t.y + t.z + t.w;
    float s2 = t.x * t.x + t.y * t.y + t.z * t.z + t.w * t.w;
    #pragma unroll
    for (int m = 32; m > 0; m >>= 1) {
        s1 += __shfl_xor(s1, m);
        s2 += __shfl_xor(s2, m);
    }
    float mu = s1 * (1.f / 256.f);
    float var = s2 * (1.f / 256.f) - mu * mu;
    float inv = rsqrtf(var + 1e-5f);
    int k = lane * 4;
    float o0 = (t.x - mu) * inv * b2f(g[k+0]) + b2f(b[k+0]);
    float o1 = (t.y - mu) * inv * b2f(g[k+1]) + b2f(b[k+1]);
    float o2 = (t.z - mu) * inv * b2f(g[k+2]) + b2f(b[k+2]);
    float o3 = (t.w - mu) * inv * b2f(g[k+3]) + b2f(b[k+3]);
    uint2 st = {pack2(o0, o1), pack2(o2, o3)};
    *reinterpret_cast<uint2*>(out + r * 256 + k) = st;
}

// ---------------- MFMA GEMM: out[M,J] = A @ WT^T + bias; cols split by blockIdx.y ----------------
template <int K, int J, int MODE>
__global__ __launch_bounds__(256) void gemm_mfma(const bf16* __restrict__ A,
                                                 const bf16* __restrict__ WT,
                                                 const bf16* __restrict__ bias,
                                                 float* __restrict__ outf,
                                                 const void* __restrict__ resraw,
                                                 const float* __restrict__ resf,
                                                 const int* __restrict__ flags) {
    constexpr int LDK = K + 8;
    __shared__ bf16 As[32 * LDK];
    int tid = threadIdx.x;
    int row0 = blockIdx.x * 32;
    int col0 = blockIdx.y * 64;
    for (int t = tid; t < 32 * (K / 8); t += 256) {
        int r = t / (K / 8), kq = t % (K / 8);
        uint4 u = {0u, 0u, 0u, 0u};
        if (row0 + r < N_Q)
            u = *reinterpret_cast<const uint4*>(A + (size_t)(row0 + r) * K + kq * 8);
        *reinterpret_cast<uint4*>(&As[r * LDK + kq * 8]) = u;
    }
    __syncthreads();
    int wave = tid >> 6, lane = tid & 63;
    int l = lane & 15, quad = lane >> 4;
    int rh = wave >> 1, ch = wave & 1;
    constexpr int NK = K / 32;
    short8 afr[NK];
    const bf16* arow = &As[(rh * 16 + l) * LDK + quad * 8];
    #pragma unroll
    for (int ks = 0; ks < NK; ks++)
        afr[ks] = *reinterpret_cast<const short8*>(arow + ks * 32);
    int fdt = flags[0];
    #pragma unroll
    for (int ct = 0; ct < 2; ct++) {
        int col = col0 + ch * 32 + ct * 16 + l;
        const bf16* wrow = WT + (size_t)col * K + quad * 8;
        f32x4 acc = {0.f, 0.f, 0.f, 0.f};
        #pragma unroll
        for (int ks = 0; ks < NK; ks++) {
            short8 bfr = *reinterpret_cast<const short8*>(wrow + ks * 32);
            acc = mfma16(afr[ks], bfr, acc);
        }
        float bb = b2f(bias[col]);
        #pragma unroll
        for (int r = 0; r < 4; r++) {
            int row = row0 + rh * 16 + quad * 4 + r;
            if (row >= N_Q) continue;
            long o = (long)row * J + col;
            float v = acc[r] + bb;
            if (MODE == 2) outf[o] = v + load_any(resraw, o, fdt);
            else           outf[o] = v + resf[o];
        }
    }
}

// ---------------- Dual MFMA GEMM (concat cols J1|J2); out1=tanh*scale bf16, out2 plain bf16 ----
template <int K, int J1, int J2>
__global__ __launch_bounds__(256) void gemm_dual(const bf16* __restrict__ A,
                                                 const bf16* __restrict__ WT1,
                                                 const bf16* __restrict__ b1, float scale,
                                                 bf16* __restrict__ out1,
                                                 const bf16* __restrict__ WT2,
                                                 const bf16* __restrict__ b2,
                                                 bf16* __restrict__ out2) {
    constexpr int LDK = K + 8;
    __shared__ bf16 As[32 * LDK];
    int tid = threadIdx.x;
    int row0 = blockIdx.x * 32;
    int col0 = blockIdx.y * 64;
    for (int t = tid; t < 32 * (K / 8); t += 256) {
        int r = t / (K / 8), kq = t % (K / 8);
        uint4 u = {0u, 0u, 0u, 0u};
        if (row0 + r < N_Q)
            u = *reinterpret_cast<const uint4*>(A + (size_t)(row0 + r) * K + kq * 8);
        *reinterpret_cast<uint4*>(&As[r * LDK + kq * 8]) = u;
    }
    __syncthreads();
    int wave = tid >> 6, lane = tid & 63;
    int l = lane & 15, quad = lane >> 4;
    int rh = wave >> 1, ch = wave & 1;
    constexpr int NK = K / 32;
    short8 afr[NK];
    const bf16* arow = &As[(rh * 16 + l) * LDK + quad * 8];
    #pragma unroll
    for (int ks = 0; ks < NK; ks++)
        afr[ks] = *reinterpret_cast<const short8*>(arow + ks * 32);
    #pragma unroll
    for (int ct = 0; ct < 2; ct++) {
        int jg = col0 + ch * 32 + ct * 16 + l;
        int in1 = jg < J1;
        int cl = in1 ? jg : jg - J1;
        const bf16* wrow = (in1 ? WT1 : WT2) + (size_t)cl * K + quad * 8;
        f32x4 acc = {0.f, 0.f, 0.f, 0.f};
        #pragma unroll
        for (int ks = 0; ks < NK; ks++) {
            short8 bfr = *reinterpret_cast<const short8*>(wrow + ks * 32);
            acc = mfma16(afr[ks], bfr, acc);
        }
        float bb = b2f(in1 ? b1[cl] : b2[cl]);
        #pragma unroll
        for (int r = 0; r < 4; r++) {
            int row = row0 + rh * 16 + quad * 4 + r;
            if (row >= N_Q) continue;
            float v = acc[r] + bb;
            if (in1) out1[(long)row * J1 + cl] = f2b(tanhf(v) * scale);
            else     out2[(long)row * J2 + cl] = f2b(v);
        }
    }
}

// ---------------- Fused MFMA FFN: LN3 -> @w1T,relu -> @w2T -> +x -> out ----------------
__global__ __launch_bounds__(256) void ffn_mfma(const float* __restrict__ x,
                                                const bf16* __restrict__ g3,
                                                const bf16* __restrict__ b3,
                                                const bf16* __restrict__ w1T,
                                                const bf16* __restrict__ b1,
                                                const bf16* __restrict__ w2T,
                                                const bf16* __restrict__ b2v,
                                                void* __restrict__ out,
                                                const int* __restrict__ flags) {
    constexpr int LDH = DFF + 8;
    constexpr int LDX = D_MODEL + 8;
    __shared__ bf16 hbuf[16 * LDH];
    bf16* xl = hbuf;
    int tid = threadIdx.x;
    int row0 = blockIdx.x * 16;
    {
        int r = tid >> 4, lr = tid & 15;
        const float* xr = x + (long)(row0 + r) * 256 + lr * 16;
        float vals[16];
        float s1 = 0.f, s2 = 0.f;
        #pragma unroll
        for (int i = 0; i < 16; i++) {
            float v = xr[i];
            vals[i] = v; s1 += v; s2 += v * v;
        }
        #pragma unroll
        for (int off = 8; off > 0; off >>= 1) {
            s1 += __shfl_down(s1, off, 16);
            s2 += __shfl_down(s2, off, 16);
        }
        s1 = __shfl(s1, 0, 16);
        s2 = __shfl(s2, 0, 16);
        float mu = s1 * (1.f / 256.f);
        float var = s2 * (1.f / 256.f) - mu * mu;
        float inv = rsqrtf(var + 1e-5f);
        #pragma unroll
        for (int i = 0; i < 16; i++) {
            int k = lr * 16 + i;
            xl[r * LDX + k] = f2b((vals[i] - mu) * inv * b2f(g3[k]) + b2f(b3[k]));
        }
    }
    __syncthreads();
    int wave = tid >> 6, lane = tid & 63;
    int l = lane & 15, quad = lane >> 4;
    short8 afr[8];
    {
        const bf16* arow = xl + l * LDX + quad * 8;
        #pragma unroll
        for (int ks = 0; ks < 8; ks++)
            afr[ks] = *reinterpret_cast<const short8*>(arow + ks * 32);
    }
    __syncthreads();
    for (int ct = 0; ct < 16; ct++) {
        int col = wave * 256 + ct * 16 + l;
        const bf16* wrow = w1T + (size_t)col * 256 + quad * 8;
        f32x4 acc = {0.f, 0.f, 0.f, 0.f};
        #pragma unroll
        for (int ks = 0; ks < 8; ks++) {
            short8 bfr = *reinterpret_cast<const short8*>(wrow + ks * 32);
            acc = mfma16(afr[ks], bfr, acc);
        }
        float bb = b2f(b1[col]);
        #pragma unroll
        for (int r = 0; r < 4; r++)
            hbuf[(quad * 4 + r) * LDH + col] = f2b(fmaxf(acc[r] + bb, 0.f));
    }
    __syncthreads();
    int fdt = flags[0];
    for (int ct = 0; ct < 4; ct++) {
        int col = wave * 64 + ct * 16 + l;
        const bf16* wrow = w2T + (size_t)col * 1024 + quad * 8;
        const bf16* hrow = hbuf + l * LDH + quad * 8;
        f32x4 acc = {0.f, 0.f, 0.f, 0.f};
        #pragma unroll 8
        for (int ks = 0; ks < 32; ks++) {
            short8 a2 = *reinterpret_cast<const short8*>(hrow + ks * 32);
            short8 bfr = *reinterpret_cast<const short8*>(wrow + ks * 32);
            acc = mfma16(a2, bfr, acc);
        }
        float bb = b2f(b2v[col]);
        #pragma unroll
        for (int r = 0; r < 4; r++) {
            long o = (long)(row0 + quad * 4 + r) * 256 + col;
            store_any(out, o, fdt, x[o] + acc[r] + bb);
        }
    }
}

// ---------------- Temporal sampling (8 q/block, 8 ch/thread, conditional corners) ----------------
__global__ __launch_bounds__(256) void temporal_kernel(const bf16* __restrict__ ai,
                                                       const bf16* __restrict__ toffB,
                                                       const bf16* __restrict__ twlB,
                                                       const void* __restrict__ ref2d,
                                                       const void* __restrict__ ego,
                                                       const int* __restrict__ flags,
                                                       bf16* __restrict__ tfB) {
    int tid = threadIdx.x;
    int ql = tid >> 5, t = tid & 31;
    int g = t >> 2, q4 = t & 3;
    long n0 = (long)blockIdx.x * 8;
    __shared__ float s_toff[8][8][17];
    __shared__ float s_twl[8][64];
    __shared__ float s_base[8][4];
    for (int i = tid; i < 8 * 128; i += 256) {
        int q = i >> 7, j = i & 127;
        int si = j >> 6, r = j & 63, gg = r >> 3, w = r & 7;
        s_toff[q][gg][si * 8 + w] = b2f(toffB[n0 * 128 + i]);
    }
    for (int i = tid; i < 8 * 64; i += 256) s_twl[i >> 6][i & 63] = b2f(twlB[n0 * 64 + i]);
    if (tid < 8) {
        int f = flags[0];
        float rx = load_any(ref2d, (n0 + tid) * 2, f), ry = load_any(ref2d, (n0 + tid) * 2 + 1, f);
        s_base[tid][0] = rx + load_any(ego, 0, f); s_base[tid][1] = ry + load_any(ego, 1, f);
        s_base[tid][2] = rx;                       s_base[tid][3] = ry;
    }
    __syncthreads();
    float acc[8];
    #pragma unroll
    for (int i = 0; i < 8; i++) acc[i] = 0.f;
    int choff = g * 32 + q4 * 8;
    #pragma unroll
    for (int si = 0; si < 2; si++) {
        float l0 = s_twl[ql][si * 32 + g * 4 + 0], l1 = s_twl[ql][si * 32 + g * 4 + 1];
        float l2 = s_twl[ql][si * 32 + g * 4 + 2], l3 = s_twl[ql][si * 32 + g * 4 + 3];
        float mx = fmaxf(fmaxf(l0, l1), fmaxf(l2, l3));
        float e0 = __expf(l0 - mx), e1 = __expf(l1 - mx);
        float e2 = __expf(l2 - mx), e3 = __expf(l3 - mx);
        float inv = 1.f / (e0 + e1 + e2 + e3);
        float wts[4] = {e0 * inv, e1 * inv, e2 * inv, e3 * inv};
        int aoff = si * 256;
        float bx = s_base[ql][si * 2], by = s_base[ql][si * 2 + 1];
        #pragma unroll
        for (int pt = 0; pt < 4; pt++) {
            float u = bx + s_toff[ql][g][si * 8 + pt * 2 + 0];
            float v = by + s_toff[ql][g][si * 8 + pt * 2 + 1];
            float ix = u * (float)BW - 0.5f;
            float iy = v * (float)BH - 0.5f;
            float x0f = floorf(ix), y0f = floorf(iy);
            int x0 = (int)x0f, y0 = (int)y0f;
            float wx1 = ix - x0f, wy1 = iy - y0f;
            float wx0 = 1.f - wx1, wy0 = 1.f - wy1;
            #pragma unroll
            for (int cy = 0; cy < 2; cy++) {
                int yy = y0 + cy;
                if ((unsigned)yy >= BH) continue;
                float wy = cy ? wy1 : wy0;
                #pragma unroll
                for (int cx = 0; cx < 2; cx++) {
                    int xx = x0 + cx;
                    if ((unsigned)xx >= BW) continue;
                    float wq = wts[pt] * wy * (cx ? wx1 : wx0);
                    uint4 uu = *reinterpret_cast<const uint4*>(
                        ai + (long)(yy * BW + xx) * 512 + aoff + choff);
                    acc[0] += wq * __uint_as_float(uu.x << 16);
                    acc[1] += wq * __uint_as_float(uu.x & 0xFFFF0000u);
                    acc[2] += wq * __uint_as_float(uu.y << 16);
                    acc[3] += wq * __uint_as_float(uu.y & 0xFFFF0000u);
                    acc[4] += wq * __uint_as_float(uu.z << 16);
                    acc[5] += wq * __uint_as_float(uu.z & 0xFFFF0000u);
                    acc[6] += wq * __uint_as_float(uu.w << 16);
                    acc[7] += wq * __uint_as_float(uu.w & 0xFFFF0000u);
                }
            }
        }
    }
    uint4 o;
    o.x = pack2(acc[0] * 0.5f, acc[1] * 0.5f);
    o.y = pack2(acc[2] * 0.5f, acc[3] * 0.5f);
    o.z = pack2(acc[4] * 0.5f, acc[5] * 0.5f);
    o.w = pack2(acc[6] * 0.5f, acc[7] * 0.5f);
    *reinterpret_cast<uint4*>(tfB + (n0 + ql) * 256 + choff) = o;
}

// ---------------- Spatial v6b: ONE query per wave (zero divergence), 4 ch/thread ----------------
// 128 thr = 2 waves = 2 queries. lane: g = t>>3 (head), l8 = t&7 (channel chunk of 4).
__global__ __launch_bounds__(128) void spatial_kernel(const bf16* __restrict__ soffB,
                                                      const bf16* __restrict__ swlB,
                                                      const void* __restrict__ refcam,
                                                      const void* __restrict__ bmask,
                                                      const bf16* __restrict__ imgT,
                                                      const void* __restrict__ img_raw,
                                                      int use_imgT,
                                                      const int* __restrict__ flags,
                                                      bf16* __restrict__ sfB) {
    int tid = threadIdx.x;
    int ql = tid >> 6, t = tid & 63;
    int g = t >> 3, l8 = t & 7;
    long n0 = (long)blockIdx.x * 2;
    __shared__ float s_soff[2][8][33];
    __shared__ float s_swl[2][144];        // [q][j*9 + g]
    __shared__ float s_ref[2][NC][PP][2];
    __shared__ int   s_vis[2][NC][PP];
    for (int i = tid; i < 2 * 256; i += 128) {
        int q = i >> 8, j = i & 255;
        s_soff[q][j >> 5][j & 31] = b2f(soffB[n0 * 256 + i]);
    }
    for (int i = tid; i < 2 * 128; i += 128) {
        int q = i >> 7, jr = i & 127;
        int gg = jr >> 4, j = jr & 15;
        s_swl[q][j * 9 + gg] = b2f(swlB[n0 * 128 + i]);
    }
    int fdt = flags[0], msz = flags[1];
    if (tid < 2 * 48) {
        int q = tid / 48, r = tid % 48;
        s_ref[q][r >> 3][(r & 7) >> 1][r & 1] =
            load_any(refcam, ((long)(r >> 3) * N_Q + n0 + q) * 8 + (r & 7), fdt);
    }
    if (tid >= 80 && tid < 80 + 2 * 24) {   // 48 entries, window [80,128) fits the block
        int tt = tid - 80;
        int q = tt / 24, r = tt % 24; int c = r >> 2, p = r & 3;
        long idx = ((long)c * N_Q + n0 + q) * 4 + p;
        int v;
        if (msz == 1)      v = ((const unsigned char*)bmask)[idx] != 0;
        else if (msz == 2) v = ((const unsigned short*)bmask)[idx] != 0;
        else if (msz == 4) v = ((const unsigned int*)bmask)[idx] != 0u;
        else               v = ((const unsigned long long*)bmask)[idx] != 0ULL;
        s_vis[q][c][p] = v;
    }
    __syncthreads();
    // hoisted softmax numerators (shift-invariant masked softmax)
    float ew[16];
    {
        float lw[16], mx = -3e38f;
        #pragma unroll
        for (int j = 0; j < 16; j++) { lw[j] = s_swl[ql][j * 9 + g]; mx = fmaxf(mx, lw[j]); }
        #pragma unroll
        for (int j = 0; j < 16; j++) ew[j] = __expf(lw[j] - mx);
    }
    float acc[4] = {0.f, 0.f, 0.f, 0.f};
    float cnt = 0.f;
    int choff = g * 32 + l8 * 4;
    for (int c = 0; c < NC; c++) {
        int m0 = s_vis[ql][c][0], m1 = s_vis[ql][c][1];
        int m2 = s_vis[ql][c][2], m3 = s_vis[ql][c][3];
        if (!(m0 | m1 | m2 | m3)) continue;
        cnt += 1.f;
        float sum = 0.f;
        #pragma unroll
        for (int j = 0; j < 16; j++)
            sum += s_vis[ql][c][j >> 2] ? ew[j] : 0.f;
        float inv = 1.f / fmaxf(sum, 1e-20f);
        const bf16* img = imgT + (long)c * HF * WF * 256 + choff;
        #pragma unroll
        for (int p = 0; p < PP; p++) {
            if (!s_vis[ql][c][p]) continue;
            float rx = s_ref[ql][c][p][0], ry = s_ref[ql][c][p][1];
            #pragma unroll
            for (int s = 0; s < PS; s++) {
                float wi = ew[p * 4 + s] * inv;
                float u = rx + s_soff[ql][g][p * 8 + s * 2 + 0];
                float v = ry + s_soff[ql][g][p * 8 + s * 2 + 1];
                float ix = u * (float)WF - 0.5f, iy = v * (float)HF - 0.5f;
                float x0f = floorf(ix), y0f = floorf(iy);
                int x0 = (int)x0f, y0 = (int)y0f;
                float wx1 = ix - x0f, wy1 = iy - y0f;
                float wx0 = 1.f - wx1, wy0 = 1.f - wy1;
                #pragma unroll
                for (int cy = 0; cy < 2; cy++) {
                    int yy = y0 + cy;
                    if ((unsigned)yy >= HF) continue;
                    float wy = cy ? wy1 : wy0;
                    #pragma unroll
                    for (int cx = 0; cx < 2; cx++) {
                        int xx = x0 + cx;
                        if ((unsigned)xx >= WF) continue;
                        float wq = wi * wy * (cx ? wx1 : wx0);
                        if (use_imgT) {
                            uint2 uu = *reinterpret_cast<const uint2*>(
                                img + (long)(yy * WF + xx) * 256);
                            acc[0] += wq * __uint_as_float(uu.x << 16);
                            acc[1] += wq * __uint_as_float(uu.x & 0xFFFF0000u);
                            acc[2] += wq * __uint_as_float(uu.y << 16);
                            acc[3] += wq * __uint_as_float(uu.y & 0xFFFF0000u);
                        } else {
                            #pragma unroll
                            for (int e = 0; e < 4; e++)
                                acc[e] += wq * load_any(img_raw,
                                    (((long)c * 256 + choff + e) * HF + yy) * WF + xx, fdt);
                        }
                    }
                }
            }
        }
    }
    float invc = 1.f / fmaxf(cnt, 1.f);
    uint2 o;
    o.x = pack2(acc[0] * invc, acc[1] * invc);
    o.y = pack2(acc[2] * invc, acc[3] * invc);
    *reinterpret_cast<uint2*>(sfB + (n0 + ql) * 256 + choff) = o;
}

// bf16 element offsets inside the weight region (matrices stored TRANSPOSED [J][K])
#define W_TOFF_W 0
#define W_TOFF_B 65536
#define W_TWT_W  65664
#define W_TWT_B  98432
#define W_TOUT_W 98496
#define W_TOUT_B 164032
#define W_SOFF_W 164288
#define W_SOFF_B 229824
#define W_SWT_W  230080
#define W_SWT_B  262848
#define W_SOUT_W 262976
#define W_SOUT_B 328512
#define W_FFN_W1 328768
#define W_FFN_B1 590912
#define W_FFN_W2 591936
#define W_FFN_B2 854080
#define W_LN1_G  854336
#define W_LN1_B  854592
#define W_LN2_G  854848
#define W_LN2_B  855104
#define W_LN3_G  855360
#define W_LN3_B  855616

// byte offsets in workspace (total ~35.6 MB)
#define OB_WGT   0
#define OB_FLAGS 1711744
#define OB_AI    1712640
#define OB_TF    11952640
#define OB_X     17072640
#define OB_T4    27312640
#define OB_IMG   31152640
#define WS_NEED_IMG 35576320ULL

extern "C" void kernel_launch(void* const* d_in, const int* in_sizes, int n_in,
                              void* d_out, int out_size, void* d_ws, size_t ws_size,
                              hipStream_t stream) {
    char* W8 = (char*)d_ws;
    bf16*  wgt   = (bf16*)(W8 + OB_WGT);
    int*   flags = (int*)(W8 + OB_FLAGS);
    bf16*  ai    = (bf16*)(W8 + OB_AI);                 // N x 512, pb | q1
    bf16*  q2B   = ai;                                  // N x 256 (after temporal)
    bf16*  sfB   = (bf16*)(W8 + OB_AI + 5120000);       // N x 256
    bf16*  tfB   = (bf16*)(W8 + OB_TF);                 // N x 256
    bf16*  soffB = tfB;                                 // N x 256 (after t_out gemm)
    float* x     = (float*)(W8 + OB_X);                 // N x 256 f32 trunk
    bf16*  toffB = (bf16*)(W8 + OB_T4);                 // N x 128
    bf16*  twlB  = (bf16*)(W8 + OB_T4 + 2560000);       // N x 64
    bf16*  swlB  = toffB;                               // N x 128 (after temporal)
    bf16*  imgT  = (bf16*)(W8 + OB_IMG);                // NC*HF*WF*256
    int use_imgT = (ws_size >= WS_NEED_IMG) ? 1 : 0;

    detect_kernel<<<1, 256, 0, stream>>>(d_in[22], d_in[28], flags);

    {   // unified prep: 8 transposes + 14 flat cvts + img transpose
        PrepDesc pd;
        const int tsrc[8] = {6, 8, 10, 12, 14, 16, 18, 20};
        const int toff[8] = {W_TOFF_W, W_TWT_W, W_TOUT_W, W_SOFF_W, W_SWT_W, W_SOUT_W,
                             W_FFN_W1, W_FFN_W2};
        const int tR[8] = {512, 512, 256, 256, 256, 256, 256, 1024};
        const int tC[8] = {128, 64, 256, 256, 128, 256, 1024, 256};
        const int fsrc[14] = {7, 9, 11, 13, 15, 17, 19, 21, 22, 23, 24, 25, 26, 27};
        const int foff[14] = {W_TOFF_B, W_TWT_B, W_TOUT_B, W_SOFF_B, W_SWT_B, W_SOUT_B,
                              W_FFN_B1, W_FFN_B2, W_LN1_G, W_LN1_B, W_LN2_G, W_LN2_B,
                              W_LN3_G, W_LN3_B};
        const int fcnt[14] = {128, 64, 256, 256, 128, 256, 1024, 256, 256, 256, 256, 256, 256, 256};
        int a = 0, blk = 0;
        for (int i = 0; i < 8; i++, a++) {
            pd.src[a] = d_in[tsrc[i]]; pd.dst_off[a] = toff[i];
            pd.count[a] = tR[i] * tC[i]; pd.R[a] = tR[i]; pd.C[a] = tC[i];
            pd.type[a] = 1; pd.blk_start[a] = blk; blk += (pd.count[a] + 255) / 256;
        }
        for (int i = 0; i < 14; i++, a++) {
            pd.src[a] = d_in[fsrc[i]]; pd.dst_off[a] = foff[i];
            pd.count[a] = fcnt[i]; pd.R[a] = 0; pd.C[a] = 0;
            pd.type[a] = 0; pd.blk_start[a] = blk; blk += (pd.count[a] + 255) / 256;
        }
        pd.src[a] = d_in[2]; pd.dst_off[a] = 0;
        pd.count[a] = use_imgT ? NC * HF * WF * 256 : 0;
        pd.R[a] = 0; pd.C[a] = 0; pd.type[a] = 2; pd.blk_start[a] = blk;
        blk += (pd.count[a] + 255) / 256;
        pd.blk_start[NP] = blk;
        prep_kernel<<<blk, 256, 0, stream>>>(pd, wgt, imgT, flags);
    }

    ln12_kernel<<<5000, 256, 0, stream>>>(d_in[1], d_in[0], flags,
                                          wgt + W_LN1_G, wgt + W_LN1_B, ai);
    gemm_dual<512, 128, 64><<<dim3(313, 3), 256, 0, stream>>>(ai,
        wgt + W_TOFF_W, wgt + W_TOFF_B, T_RAD, toffB,
        wgt + W_TWT_W, wgt + W_TWT_B, twlB);
    temporal_kernel<<<1250, 256, 0, stream>>>(ai, toffB, twlB, d_in[3], d_in[5], flags, tfB);
    gemm_mfma<256, 256, 2><<<dim3(313, 4), 256, 0, stream>>>(tfB, wgt + W_TOUT_W, wgt + W_TOUT_B,
        x, d_in[0], nullptr, flags);
    ln_kernel<<<2500, 256, 0, stream>>>(x, wgt + W_LN2_G, wgt + W_LN2_B, q2B);
    gemm_dual<256, 256, 128><<<dim3(313, 6), 256, 0, stream>>>(q2B,
        wgt + W_SOFF_W, wgt + W_SOFF_B, S_RAD, soffB,
        wgt + W_SWT_W, wgt + W_SWT_B, swlB);
    spatial_kernel<<<5000, 128, 0, stream>>>(soffB, swlB, d_in[4], d_in[28], imgT, d_in[2],
                                             use_imgT, flags, sfB);
    gemm_mfma<256, 256, 3><<<dim3(313, 4), 256, 0, stream>>>(sfB, wgt + W_SOUT_W, wgt + W_SOUT_B,
        x, nullptr, x, flags);
    ffn_mfma<<<625, 256, 0, stream>>>(x, wgt + W_LN3_G, wgt + W_LN3_B,
                                      wgt + W_FFN_W1, wgt + W_FFN_B1,
                                      wgt + W_FFN_W2, wgt + W_FFN_B2, d_out, flags);
}

// Round 11
// 537.604 us; speedup vs baseline: 1.0090x; 1.0090x over previous
//
#include <hip/hip_runtime.h>
#include <hip/hip_bf16.h>
#include <hip/hip_fp16.h>

#define N_Q 10000
#define D_MODEL 256
#define NH 8
#define PT 4
#define PP 4
#define PS 4
#define DFF 1024
#define NC 6
#define HF 24
#define WF 60
#define BH 100
#define BW 100
#define T_RAD 0.15f
#define S_RAD 0.12f

typedef __hip_bfloat16 bf16;
typedef __attribute__((ext_vector_type(8))) short short8;
typedef __attribute__((ext_vector_type(4))) float f32x4;

__device__ __forceinline__ float b2f(bf16 v) { return __bfloat162float(v); }
__device__ __forceinline__ bf16 f2b(float v) { return __float2bfloat16(v); }

__device__ __forceinline__ f32x4 mfma16(short8 a, short8 b, f32x4 c) {
    return __builtin_amdgcn_mfma_f32_16x16x32_bf16(a, b, c, 0, 0, 0);
}

// dtype-adaptive loads/stores; f: 0=f32, 1=bf16, 2=f16
__device__ __forceinline__ float load_any(const void* p, long i, int f) {
    if (f == 0) return ((const float*)p)[i];
    if (f == 1) return b2f(((const bf16*)p)[i]);
    return __half2float(((const __half*)p)[i]);
}
__device__ __forceinline__ void store_any(void* p, long i, int f, float v) {
    if (f == 0)      ((float*)p)[i] = v;
    else if (f == 1) ((bf16*)p)[i] = f2b(v);
    else             ((__half*)p)[i] = __float2half(v);
}

__device__ __forceinline__ unsigned pack2(float a, float b) {
    bf16 x = f2b(a), y = f2b(b);
    unsigned short ux = *(unsigned short*)&x, uy = *(unsigned short*)&y;
    return (unsigned)ux | ((unsigned)uy << 16);
}

// ---------------- dtype / mask-width detection (parallel) ----------------
__global__ __launch_bounds__(256) void detect_kernel(const void* __restrict__ ln1g,
                                                     const void* __restrict__ mask,
                                                     int* __restrict__ flags) {
    __shared__ int sh[6];
    int tid = threadIdx.x;
    if (tid < 6) sh[tid] = (tid == 0 || tid == 2 || tid == 4) ? 1 : 0;
    __syncthreads();
    const unsigned long long* m64 = (const unsigned long long*)mask;
    const unsigned int*       m32 = (const unsigned int*)mask;
    const unsigned short*     m16 = (const unsigned short*)mask;
    int lok8 = 1, lones8 = 0, lok4 = 1, lones4 = 0, lok2 = 1, lones2 = 0;
    for (int i = tid; i < 480; i += 256) {
        if (i < 120) {
            unsigned long long v = m64[i];
            if (v == 1ULL) lones8++; else if (v != 0ULL) lok8 = 0;
        }
        if (i < 240) {
            unsigned int v = m32[i];
            if (v == 1u || v == 0x3F800000u) lones4++; else if (v != 0u) lok4 = 0;
        }
        unsigned short v = m16[i];
        if (v == 1 || v == 0x3F80) lones2++; else if (v != 0) lok2 = 0;
    }
    atomicAnd(&sh[0], lok8); atomicAdd(&sh[1], lones8);
    atomicAnd(&sh[2], lok4); atomicAdd(&sh[3], lones4);
    atomicAnd(&sh[4], lok2); atomicAdd(&sh[5], lones2);
    __syncthreads();
    if (tid == 0) {
        unsigned short u0 = ((const unsigned short*)ln1g)[0];
        flags[0] = (u0 == 0x3F80) ? 1 : (u0 == 0x3C00 ? 2 : 0);
        int ms;
        if (sh[0] && sh[1] > 30)       ms = 8;
        else if (sh[2] && sh[3] > 60)  ms = 4;
        else if (sh[4] && sh[5] > 120) ms = 2;
        else                           ms = 1;
        flags[1] = ms;
    }
}

// ---------------- unified weight/image prep: transposes + flat cvt + img transpose ----------------
#define NP 23
struct PrepDesc {
    const void* src[NP];
    int dst_off[NP];
    int count[NP];
    int R[NP];
    int C[NP];
    int type[NP];       // 0 flat cvt, 1 transpose, 2 img transpose
    int blk_start[NP + 1];
};
__global__ __launch_bounds__(256) void prep_kernel(PrepDesc pd, bf16* __restrict__ wgt,
                                                   bf16* __restrict__ imgT,
                                                   const int* __restrict__ flags) {
    int blk = blockIdx.x;
    int a = 0;
    while (a < NP - 1 && blk >= pd.blk_start[a + 1]) a++;
    int i = (blk - pd.blk_start[a]) * 256 + threadIdx.x;
    if (i >= pd.count[a]) return;
    int f = flags[0];
    int ty = pd.type[a];
    if (ty == 0) {
        wgt[pd.dst_off[a] + i] = f2b(load_any(pd.src[a], i, f));
    } else if (ty == 1) {
        int R = pd.R[a], C = pd.C[a];
        int c = i / R, r = i % R;
        wgt[pd.dst_off[a] + i] = f2b(load_any(pd.src[a], (long)r * C + c, f));
    } else {
        int ch = i & 255;
        int t = i >> 8;
        int xx = t % WF; t /= WF;
        int yy = t % HF;
        int c  = t / HF;
        long src = (((long)(c * 256) + ch) * HF + yy) * WF + xx;
        imgT[i] = f2b(load_any(pd.src[a], src, f));
    }
}

// ---------------- LN1 over prev_bev & query, wave-per-row -> ai[N,512] ----------------
__global__ __launch_bounds__(256) void ln12_kernel(const void* __restrict__ pb,
                                                   const void* __restrict__ q,
                                                   const int* __restrict__ flags,
                                                   const bf16* __restrict__ g,
                                                   const bf16* __restrict__ b,
                                                   bf16* __restrict__ out) {
    int wv = threadIdx.x >> 6, lane = threadIdx.x & 63;
    long row = (long)blockIdx.x * 4 + wv;
    const void* src; long r; int ooff;
    if (row < N_Q) { src = pb; r = row; ooff = 0; }
    else           { src = q;  r = row - N_Q; ooff = 256; }
    int f = flags[0];
    float v0, v1, v2, v3;
    if (f == 0) {
        float4 t = ((const float4*)src)[r * 64 + lane];
        v0 = t.x; v1 = t.y; v2 = t.z; v3 = t.w;
    } else {
        uint2 t = ((const uint2*)src)[r * 64 + lane];
        if (f == 1) {
            v0 = __uint_as_float(t.x << 16); v1 = __uint_as_float(t.x & 0xFFFF0000u);
            v2 = __uint_as_float(t.y << 16); v3 = __uint_as_float(t.y & 0xFFFF0000u);
        } else {
            __half2 h0 = *(__half2*)&t.x, h1 = *(__half2*)&t.y;
            v0 = __half2float(h0.x); v1 = __half2float(h0.y);
            v2 = __half2float(h1.x); v3 = __half2float(h1.y);
        }
    }
    float s1 = v0 + v1 + v2 + v3;
    float s2 = v0 * v0 + v1 * v1 + v2 * v2 + v3 * v3;
    #pragma unroll
    for (int m = 32; m > 0; m >>= 1) {
        s1 += __shfl_xor(s1, m);
        s2 += __shfl_xor(s2, m);
    }
    float mu = s1 * (1.f / 256.f);
    float var = s2 * (1.f / 256.f) - mu * mu;
    float inv = rsqrtf(var + 1e-5f);
    int k = lane * 4;
    float o0 = (v0 - mu) * inv * b2f(g[k+0]) + b2f(b[k+0]);
    float o1 = (v1 - mu) * inv * b2f(g[k+1]) + b2f(b[k+1]);
    float o2 = (v2 - mu) * inv * b2f(g[k+2]) + b2f(b[k+2]);
    float o3 = (v3 - mu) * inv * b2f(g[k+3]) + b2f(b[k+3]);
    uint2 st = {pack2(o0, o1), pack2(o2, o3)};
    *reinterpret_cast<uint2*>(out + r * 512 + ooff + k) = st;
}

// ---------------- LayerNorm (f32 in), wave-per-row -> bf16 out ----------------
__global__ __launch_bounds__(256) void ln_kernel(const float* __restrict__ in,
                                                 const bf16* __restrict__ g,
                                                 const bf16* __restrict__ b,
                                                 bf16* __restrict__ out) {
    int wv = threadIdx.x >> 6, lane = threadIdx.x & 63;
    long r = (long)blockIdx.x * 4 + wv;
    float4 t = ((const float4*)in)[r * 64 + lane];
    float s1 = t.x + t.y + t.z + t.w;
    float s2 = t.x * t.x + t.y * t.y + t.z * t.z + t.w * t.w;
    #pragma unroll
    for (int m = 32; m > 0; m >>= 1) {
        s1 += __shfl_xor(s1, m);
        s2 += __shfl_xor(s2, m);
    }
    float mu = s1 * (1.f / 256.f);
    float var = s2 * (1.f / 256.f) - mu * mu;
    float inv = rsqrtf(var + 1e-5f);
    int k = lane * 4;
    float o0 = (t.x - mu) * inv * b2f(g[k+0]) + b2f(b[k+0]);
    float o1 = (t.y - mu) * inv * b2f(g[k+1]) + b2f(b[k+1]);
    float o2 = (t.z - mu) * inv * b2f(g[k+2]) + b2f(b[k+2]);
    float o3 = (t.w - mu) * inv * b2f(g[k+3]) + b2f(b[k+3]);
    uint2 st = {pack2(o0, o1), pack2(o2, o3)};
    *reinterpret_cast<uint2*>(out + r * 256 + k) = st;
}

// ---------------- MFMA GEMM: out[M,J] = A @ WT^T + bias; cols split by blockIdx.y ----------------
template <int K, int J, int MODE>
__global__ __launch_bounds__(256) void gemm_mfma(const bf16* __restrict__ A,
                                                 const bf16* __restrict__ WT,
                                                 const bf16* __restrict__ bias,
                                                 float* __restrict__ outf,
                                                 const void* __restrict__ resraw,
                                                 const float* __restrict__ resf,
                                                 const int* __restrict__ flags) {
    constexpr int LDK = K + 8;
    __shared__ bf16 As[32 * LDK];
    int tid = threadIdx.x;
    int row0 = blockIdx.x * 32;
    int col0 = blockIdx.y * 64;
    for (int t = tid; t < 32 * (K / 8); t += 256) {
        int r = t / (K / 8), kq = t % (K / 8);
        uint4 u = {0u, 0u, 0u, 0u};
        if (row0 + r < N_Q)
            u = *reinterpret_cast<const uint4*>(A + (size_t)(row0 + r) * K + kq * 8);
        *reinterpret_cast<uint4*>(&As[r * LDK + kq * 8]) = u;
    }
    __syncthreads();
    int wave = tid >> 6, lane = tid & 63;
    int l = lane & 15, quad = lane >> 4;
    int rh = wave >> 1, ch = wave & 1;
    constexpr int NK = K / 32;
    short8 afr[NK];
    const bf16* arow = &As[(rh * 16 + l) * LDK + quad * 8];
    #pragma unroll
    for (int ks = 0; ks < NK; ks++)
        afr[ks] = *reinterpret_cast<const short8*>(arow + ks * 32);
    int fdt = flags[0];
    #pragma unroll
    for (int ct = 0; ct < 2; ct++) {
        int col = col0 + ch * 32 + ct * 16 + l;
        const bf16* wrow = WT + (size_t)col * K + quad * 8;
        f32x4 acc = {0.f, 0.f, 0.f, 0.f};
        #pragma unroll
        for (int ks = 0; ks < NK; ks++) {
            short8 bfr = *reinterpret_cast<const short8*>(wrow + ks * 32);
            acc = mfma16(afr[ks], bfr, acc);
        }
        float bb = b2f(bias[col]);
        #pragma unroll
        for (int r = 0; r < 4; r++) {
            int row = row0 + rh * 16 + quad * 4 + r;
            if (row >= N_Q) continue;
            long o = (long)row * J + col;
            float v = acc[r] + bb;
            if (MODE == 2) outf[o] = v + load_any(resraw, o, fdt);
            else           outf[o] = v + resf[o];
        }
    }
}

// ---------------- Dual MFMA GEMM (concat cols J1|J2); out1=tanh*scale bf16, out2 plain bf16 ----
template <int K, int J1, int J2>
__global__ __launch_bounds__(256) void gemm_dual(const bf16* __restrict__ A,
                                                 const bf16* __restrict__ WT1,
                                                 const bf16* __restrict__ b1, float scale,
                                                 bf16* __restrict__ out1,
                                                 const bf16* __restrict__ WT2,
                                                 const bf16* __restrict__ b2,
                                                 bf16* __restrict__ out2) {
    constexpr int LDK = K + 8;
    __shared__ bf16 As[32 * LDK];
    int tid = threadIdx.x;
    int row0 = blockIdx.x * 32;
    int col0 = blockIdx.y * 64;
    for (int t = tid; t < 32 * (K / 8); t += 256) {
        int r = t / (K / 8), kq = t % (K / 8);
        uint4 u = {0u, 0u, 0u, 0u};
        if (row0 + r < N_Q)
            u = *reinterpret_cast<const uint4*>(A + (size_t)(row0 + r) * K + kq * 8);
        *reinterpret_cast<uint4*>(&As[r * LDK + kq * 8]) = u;
    }
    __syncthreads();
    int wave = tid >> 6, lane = tid & 63;
    int l = lane & 15, quad = lane >> 4;
    int rh = wave >> 1, ch = wave & 1;
    constexpr int NK = K / 32;
    short8 afr[NK];
    const bf16* arow = &As[(rh * 16 + l) * LDK + quad * 8];
    #pragma unroll
    for (int ks = 0; ks < NK; ks++)
        afr[ks] = *reinterpret_cast<const short8*>(arow + ks * 32);
    #pragma unroll
    for (int ct = 0; ct < 2; ct++) {
        int jg = col0 + ch * 32 + ct * 16 + l;
        int in1 = jg < J1;
        int cl = in1 ? jg : jg - J1;
        const bf16* wrow = (in1 ? WT1 : WT2) + (size_t)cl * K + quad * 8;
        f32x4 acc = {0.f, 0.f, 0.f, 0.f};
        #pragma unroll
        for (int ks = 0; ks < NK; ks++) {
            short8 bfr = *reinterpret_cast<const short8*>(wrow + ks * 32);
            acc = mfma16(afr[ks], bfr, acc);
        }
        float bb = b2f(in1 ? b1[cl] : b2[cl]);
        #pragma unroll
        for (int r = 0; r < 4; r++) {
            int row = row0 + rh * 16 + quad * 4 + r;
            if (row >= N_Q) continue;
            float v = acc[r] + bb;
            if (in1) out1[(long)row * J1 + cl] = f2b(tanhf(v) * scale);
            else     out2[(long)row * J2 + cl] = f2b(v);
        }
    }
}

// ---------------- Fused MFMA FFN: LN3 -> @w1T,relu -> @w2T -> +x -> out ----------------
__global__ __launch_bounds__(256) void ffn_mfma(const float* __restrict__ x,
                                                const bf16* __restrict__ g3,
                                                const bf16* __restrict__ b3,
                                                const bf16* __restrict__ w1T,
                                                const bf16* __restrict__ b1,
                                                const bf16* __restrict__ w2T,
                                                const bf16* __restrict__ b2v,
                                                void* __restrict__ out,
                                                const int* __restrict__ flags) {
    constexpr int LDH = DFF + 8;
    constexpr int LDX = D_MODEL + 8;
    __shared__ bf16 hbuf[16 * LDH];
    bf16* xl = hbuf;
    int tid = threadIdx.x;
    int row0 = blockIdx.x * 16;
    {
        int r = tid >> 4, lr = tid & 15;
        const float* xr = x + (long)(row0 + r) * 256 + lr * 16;
        float vals[16];
        float s1 = 0.f, s2 = 0.f;
        #pragma unroll
        for (int i = 0; i < 16; i++) {
            float v = xr[i];
            vals[i] = v; s1 += v; s2 += v * v;
        }
        #pragma unroll
        for (int off = 8; off > 0; off >>= 1) {
            s1 += __shfl_down(s1, off, 16);
            s2 += __shfl_down(s2, off, 16);
        }
        s1 = __shfl(s1, 0, 16);
        s2 = __shfl(s2, 0, 16);
        float mu = s1 * (1.f / 256.f);
        float var = s2 * (1.f / 256.f) - mu * mu;
        float inv = rsqrtf(var + 1e-5f);
        #pragma unroll
        for (int i = 0; i < 16; i++) {
            int k = lr * 16 + i;
            xl[r * LDX + k] = f2b((vals[i] - mu) * inv * b2f(g3[k]) + b2f(b3[k]));
        }
    }
    __syncthreads();
    int wave = tid >> 6, lane = tid & 63;
    int l = lane & 15, quad = lane >> 4;
    short8 afr[8];
    {
        const bf16* arow = xl + l * LDX + quad * 8;
        #pragma unroll
        for (int ks = 0; ks < 8; ks++)
            afr[ks] = *reinterpret_cast<const short8*>(arow + ks * 32);
    }
    __syncthreads();
    for (int ct = 0; ct < 16; ct++) {
        int col = wave * 256 + ct * 16 + l;
        const bf16* wrow = w1T + (size_t)col * 256 + quad * 8;
        f32x4 acc = {0.f, 0.f, 0.f, 0.f};
        #pragma unroll
        for (int ks = 0; ks < 8; ks++) {
            short8 bfr = *reinterpret_cast<const short8*>(wrow + ks * 32);
            acc = mfma16(afr[ks], bfr, acc);
        }
        float bb = b2f(b1[col]);
        #pragma unroll
        for (int r = 0; r < 4; r++)
            hbuf[(quad * 4 + r) * LDH + col] = f2b(fmaxf(acc[r] + bb, 0.f));
    }
    __syncthreads();
    int fdt = flags[0];
    for (int ct = 0; ct < 4; ct++) {
        int col = wave * 64 + ct * 16 + l;
        const bf16* wrow = w2T + (size_t)col * 1024 + quad * 8;
        const bf16* hrow = hbuf + l * LDH + quad * 8;
        f32x4 acc = {0.f, 0.f, 0.f, 0.f};
        #pragma unroll 8
        for (int ks = 0; ks < 32; ks++) {
            short8 a2 = *reinterpret_cast<const short8*>(hrow + ks * 32);
            short8 bfr = *reinterpret_cast<const short8*>(wrow + ks * 32);
            acc = mfma16(a2, bfr, acc);
        }
        float bb = b2f(b2v[col]);
        #pragma unroll
        for (int r = 0; r < 4; r++) {
            long o = (long)(row0 + quad * 4 + r) * 256 + col;
            store_any(out, o, fdt, x[o] + acc[r] + bb);
        }
    }
}

// ---------------- Temporal sampling (8 q/block, 8 ch/thread, conditional corners) ----------------
__global__ __launch_bounds__(256) void temporal_kernel(const bf16* __restrict__ ai,
                                                       const bf16* __restrict__ toffB,
                                                       const bf16* __restrict__ twlB,
                                                       const void* __restrict__ ref2d,
                                                       const void* __restrict__ ego,
                                                       const int* __restrict__ flags,
                                                       bf16* __restrict__ tfB) {
    int tid = threadIdx.x;
    int ql = tid >> 5, t = tid & 31;
    int g = t >> 2, q4 = t & 3;
    long n0 = (long)blockIdx.x * 8;
    __shared__ float s_toff[8][8][17];
    __shared__ float s_twl[8][64];
    __shared__ float s_base[8][4];
    for (int i = tid; i < 8 * 128; i += 256) {
        int q = i >> 7, j = i & 127;
        int si = j >> 6, r = j & 63, gg = r >> 3, w = r & 7;
        s_toff[q][gg][si * 8 + w] = b2f(toffB[n0 * 128 + i]);
    }
    for (int i = tid; i < 8 * 64; i += 256) s_twl[i >> 6][i & 63] = b2f(twlB[n0 * 64 + i]);
    if (tid < 8) {
        int f = flags[0];
        float rx = load_any(ref2d, (n0 + tid) * 2, f), ry = load_any(ref2d, (n0 + tid) * 2 + 1, f);
        s_base[tid][0] = rx + load_any(ego, 0, f); s_base[tid][1] = ry + load_any(ego, 1, f);
        s_base[tid][2] = rx;                       s_base[tid][3] = ry;
    }
    __syncthreads();
    float acc[8];
    #pragma unroll
    for (int i = 0; i < 8; i++) acc[i] = 0.f;
    int choff = g * 32 + q4 * 8;
    #pragma unroll
    for (int si = 0; si < 2; si++) {
        float l0 = s_twl[ql][si * 32 + g * 4 + 0], l1 = s_twl[ql][si * 32 + g * 4 + 1];
        float l2 = s_twl[ql][si * 32 + g * 4 + 2], l3 = s_twl[ql][si * 32 + g * 4 + 3];
        float mx = fmaxf(fmaxf(l0, l1), fmaxf(l2, l3));
        float e0 = __expf(l0 - mx), e1 = __expf(l1 - mx);
        float e2 = __expf(l2 - mx), e3 = __expf(l3 - mx);
        float inv = 1.f / (e0 + e1 + e2 + e3);
        float wts[4] = {e0 * inv, e1 * inv, e2 * inv, e3 * inv};
        int aoff = si * 256;
        float bx = s_base[ql][si * 2], by = s_base[ql][si * 2 + 1];
        #pragma unroll
        for (int pt = 0; pt < 4; pt++) {
            float u = bx + s_toff[ql][g][si * 8 + pt * 2 + 0];
            float v = by + s_toff[ql][g][si * 8 + pt * 2 + 1];
            float ix = u * (float)BW - 0.5f;
            float iy = v * (float)BH - 0.5f;
            float x0f = floorf(ix), y0f = floorf(iy);
            int x0 = (int)x0f, y0 = (int)y0f;
            float wx1 = ix - x0f, wy1 = iy - y0f;
            float wx0 = 1.f - wx1, wy0 = 1.f - wy1;
            #pragma unroll
            for (int cy = 0; cy < 2; cy++) {
                int yy = y0 + cy;
                if ((unsigned)yy >= BH) continue;
                float wy = cy ? wy1 : wy0;
                #pragma unroll
                for (int cx = 0; cx < 2; cx++) {
                    int xx = x0 + cx;
                    if ((unsigned)xx >= BW) continue;
                    float wq = wts[pt] * wy * (cx ? wx1 : wx0);
                    uint4 uu = *reinterpret_cast<const uint4*>(
                        ai + (long)(yy * BW + xx) * 512 + aoff + choff);
                    acc[0] += wq * __uint_as_float(uu.x << 16);
                    acc[1] += wq * __uint_as_float(uu.x & 0xFFFF0000u);
                    acc[2] += wq * __uint_as_float(uu.y << 16);
                    acc[3] += wq * __uint_as_float(uu.y & 0xFFFF0000u);
                    acc[4] += wq * __uint_as_float(uu.z << 16);
                    acc[5] += wq * __uint_as_float(uu.z & 0xFFFF0000u);
                    acc[6] += wq * __uint_as_float(uu.w << 16);
                    acc[7] += wq * __uint_as_float(uu.w & 0xFFFF0000u);
                }
            }
        }
    }
    uint4 o;
    o.x = pack2(acc[0] * 0.5f, acc[1] * 0.5f);
    o.y = pack2(acc[2] * 0.5f, acc[3] * 0.5f);
    o.z = pack2(acc[4] * 0.5f, acc[5] * 0.5f);
    o.w = pack2(acc[6] * 0.5f, acc[7] * 0.5f);
    *reinterpret_cast<uint4*>(tfB + (n0 + ql) * 256 + choff) = o;
}

// ---------------- Spatial v7: wave-per-query (zero divergence), 4 queries/block ----------------
// 256 thr = 4 waves = 4 queries. lane: g = t>>3 (head), l8 = t&7 (channel chunk of 4).
__global__ __launch_bounds__(256) void spatial_kernel(const bf16* __restrict__ soffB,
                                                      const bf16* __restrict__ swlB,
                                                      const void* __restrict__ refcam,
                                                      const void* __restrict__ bmask,
                                                      const bf16* __restrict__ imgT,
                                                      const void* __restrict__ img_raw,
                                                      int use_imgT,
                                                      const int* __restrict__ flags,
                                                      bf16* __restrict__ sfB) {
    int tid = threadIdx.x;
    int ql = tid >> 6, t = tid & 63;
    int g = t >> 3, l8 = t & 7;
    long n0 = (long)blockIdx.x * 4;
    __shared__ float s_soff[4][8][33];
    __shared__ float s_swl[4][144];        // [q][j*9 + g]
    __shared__ float s_ref[4][NC][PP][2];
    __shared__ int   s_vis[4][NC][PP];
    for (int i = tid; i < 4 * 256; i += 256) {
        int q = i >> 8, j = i & 255;
        s_soff[q][j >> 5][j & 31] = b2f(soffB[n0 * 256 + i]);
    }
    for (int i = tid; i < 4 * 128; i += 256) {
        int q = i >> 7, jr = i & 127;
        int gg = jr >> 4, j = jr & 15;
        s_swl[q][j * 9 + gg] = b2f(swlB[n0 * 128 + i]);
    }
    int fdt = flags[0], msz = flags[1];
    if (tid < 4 * 48) {
        int q = tid / 48, r = tid % 48;
        s_ref[q][r >> 3][(r & 7) >> 1][r & 1] =
            load_any(refcam, ((long)(r >> 3) * N_Q + n0 + q) * 8 + (r & 7), fdt);
    }
    if (tid >= 48 * 4 && tid < 48 * 4 + 4 * 24) {   // 96 entries, window [192,288) → wait, cap 256
        // moved below; placeholder never taken
    }
    {
        int base = 0;  // stage s_vis with a dedicated clean window [0,96) on second pass
    }
    // s_vis staging: 96 entries, use tid in [160, 256)
    if (tid >= 160 && tid < 160 + 4 * 24) {
        int tt = tid - 160;
        int q = tt / 24, r = tt % 24; int c = r >> 2, p = r & 3;
        long idx = ((long)c * N_Q + n0 + q) * 4 + p;
        int v;
        if (msz == 1)      v = ((const unsigned char*)bmask)[idx] != 0;
        else if (msz == 2) v = ((const unsigned short*)bmask)[idx] != 0;
        else if (msz == 4) v = ((const unsigned int*)bmask)[idx] != 0u;
        else               v = ((const unsigned long long*)bmask)[idx] != 0ULL;
        s_vis[q][c][p] = v;
    }
    __syncthreads();
    // hoisted softmax numerators (shift-invariant masked softmax)
    float ew[16];
    {
        float lw[16], mx = -3e38f;
        #pragma unroll
        for (int j = 0; j < 16; j++) { lw[j] = s_swl[ql][j * 9 + g]; mx = fmaxf(mx, lw[j]); }
        #pragma unroll
        for (int j = 0; j < 16; j++) ew[j] = __expf(lw[j] - mx);
    }
    float acc[4] = {0.f, 0.f, 0.f, 0.f};
    float cnt = 0.f;
    int choff = g * 32 + l8 * 4;
    for (int c = 0; c < NC; c++) {
        int m0 = s_vis[ql][c][0], m1 = s_vis[ql][c][1];
        int m2 = s_vis[ql][c][2], m3 = s_vis[ql][c][3];
        if (!(m0 | m1 | m2 | m3)) continue;
        cnt += 1.f;
        float sum = 0.f;
        #pragma unroll
        for (int j = 0; j < 16; j++)
            sum += s_vis[ql][c][j >> 2] ? ew[j] : 0.f;
        float inv = 1.f / fmaxf(sum, 1e-20f);
        const bf16* img = imgT + (long)c * HF * WF * 256 + choff;
        #pragma unroll
        for (int p = 0; p < PP; p++) {
            if (!s_vis[ql][c][p]) continue;
            float rx = s_ref[ql][c][p][0], ry = s_ref[ql][c][p][1];
            #pragma unroll
            for (int s = 0; s < PS; s++) {
                float wi = ew[p * 4 + s] * inv;
                float u = rx + s_soff[ql][g][p * 8 + s * 2 + 0];
                float v = ry + s_soff[ql][g][p * 8 + s * 2 + 1];
                float ix = u * (float)WF - 0.5f, iy = v * (float)HF - 0.5f;
                float x0f = floorf(ix), y0f = floorf(iy);
                int x0 = (int)x0f, y0 = (int)y0f;
                float wx1 = ix - x0f, wy1 = iy - y0f;
                float wx0 = 1.f - wx1, wy0 = 1.f - wy1;
                #pragma unroll
                for (int cy = 0; cy < 2; cy++) {
                    int yy = y0 + cy;
                    if ((unsigned)yy >= HF) continue;
                    float wy = cy ? wy1 : wy0;
                    #pragma unroll
                    for (int cx = 0; cx < 2; cx++) {
                        int xx = x0 + cx;
                        if ((unsigned)xx >= WF) continue;
                        float wq = wi * wy * (cx ? wx1 : wx0);
                        if (use_imgT) {
                            uint2 uu = *reinterpret_cast<const uint2*>(
                                img + (long)(yy * WF + xx) * 256);
                            acc[0] += wq * __uint_as_float(uu.x << 16);
                            acc[1] += wq * __uint_as_float(uu.x & 0xFFFF0000u);
                            acc[2] += wq * __uint_as_float(uu.y << 16);
                            acc[3] += wq * __uint_as_float(uu.y & 0xFFFF0000u);
                        } else {
                            #pragma unroll
                            for (int e = 0; e < 4; e++)
                                acc[e] += wq * load_any(img_raw,
                                    (((long)c * 256 + choff + e) * HF + yy) * WF + xx, fdt);
                        }
                    }
                }
            }
        }
    }
    float invc = 1.f / fmaxf(cnt, 1.f);
    uint2 o;
    o.x = pack2(acc[0] * invc, acc[1] * invc);
    o.y = pack2(acc[2] * invc, acc[3] * invc);
    *reinterpret_cast<uint2*>(sfB + (n0 + ql) * 256 + choff) = o;
}

// bf16 element offsets inside the weight region (matrices stored TRANSPOSED [J][K])
#define W_TOFF_W 0
#define W_TOFF_B 65536
#define W_TWT_W  65664
#define W_TWT_B  98432
#define W_TOUT_W 98496
#define W_TOUT_B 164032
#define W_SOFF_W 164288
#define W_SOFF_B 229824
#define W_SWT_W  230080
#define W_SWT_B  262848
#define W_SOUT_W 262976
#define W_SOUT_B 328512
#define W_FFN_W1 328768
#define W_FFN_B1 590912
#define W_FFN_W2 591936
#define W_FFN_B2 854080
#define W_LN1_G  854336
#define W_LN1_B  854592
#define W_LN2_G  854848
#define W_LN2_B  855104
#define W_LN3_G  855360
#define W_LN3_B  855616

// byte offsets in workspace (total ~35.6 MB)
#define OB_WGT   0
#define OB_FLAGS 1711744
#define OB_AI    1712640
#define OB_TF    11952640
#define OB_X     17072640
#define OB_T4    27312640
#define OB_IMG   31152640
#define WS_NEED_IMG 35576320ULL

extern "C" void kernel_launch(void* const* d_in, const int* in_sizes, int n_in,
                              void* d_out, int out_size, void* d_ws, size_t ws_size,
                              hipStream_t stream) {
    char* W8 = (char*)d_ws;
    bf16*  wgt   = (bf16*)(W8 + OB_WGT);
    int*   flags = (int*)(W8 + OB_FLAGS);
    bf16*  ai    = (bf16*)(W8 + OB_AI);                 // N x 512, pb | q1
    bf16*  q2B   = ai;                                  // N x 256 (after temporal)
    bf16*  sfB   = (bf16*)(W8 + OB_AI + 5120000);       // N x 256
    bf16*  tfB   = (bf16*)(W8 + OB_TF);                 // N x 256
    bf16*  soffB = tfB;                                 // N x 256 (after t_out gemm)
    float* x     = (float*)(W8 + OB_X);                 // N x 256 f32 trunk
    bf16*  toffB = (bf16*)(W8 + OB_T4);                 // N x 128
    bf16*  twlB  = (bf16*)(W8 + OB_T4 + 2560000);       // N x 64
    bf16*  swlB  = toffB;                               // N x 128 (after temporal)
    bf16*  imgT  = (bf16*)(W8 + OB_IMG);                // NC*HF*WF*256
    int use_imgT = (ws_size >= WS_NEED_IMG) ? 1 : 0;

    detect_kernel<<<1, 256, 0, stream>>>(d_in[22], d_in[28], flags);

    {   // unified prep: 8 transposes + 14 flat cvts + img transpose
        PrepDesc pd;
        const int tsrc[8] = {6, 8, 10, 12, 14, 16, 18, 20};
        const int toff[8] = {W_TOFF_W, W_TWT_W, W_TOUT_W, W_SOFF_W, W_SWT_W, W_SOUT_W,
                             W_FFN_W1, W_FFN_W2};
        const int tR[8] = {512, 512, 256, 256, 256, 256, 256, 1024};
        const int tC[8] = {128, 64, 256, 256, 128, 256, 1024, 256};
        const int fsrc[14] = {7, 9, 11, 13, 15, 17, 19, 21, 22, 23, 24, 25, 26, 27};
        const int foff[14] = {W_TOFF_B, W_TWT_B, W_TOUT_B, W_SOFF_B, W_SWT_B, W_SOUT_B,
                              W_FFN_B1, W_FFN_B2, W_LN1_G, W_LN1_B, W_LN2_G, W_LN2_B,
                              W_LN3_G, W_LN3_B};
        const int fcnt[14] = {128, 64, 256, 256, 128, 256, 1024, 256, 256, 256, 256, 256, 256, 256};
        int a = 0, blk = 0;
        for (int i = 0; i < 8; i++, a++) {
            pd.src[a] = d_in[tsrc[i]]; pd.dst_off[a] = toff[i];
            pd.count[a] = tR[i] * tC[i]; pd.R[a] = tR[i]; pd.C[a] = tC[i];
            pd.type[a] = 1; pd.blk_start[a] = blk; blk += (pd.count[a] + 255) / 256;
        }
        for (int i = 0; i < 14; i++, a++) {
            pd.src[a] = d_in[fsrc[i]]; pd.dst_off[a] = foff[i];
            pd.count[a] = fcnt[i]; pd.R[a] = 0; pd.C[a] = 0;
            pd.type[a] = 0; pd.blk_start[a] = blk; blk += (pd.count[a] + 255) / 256;
        }
        pd.src[a] = d_in[2]; pd.dst_off[a] = 0;
        pd.count[a] = use_imgT ? NC * HF * WF * 256 : 0;
        pd.R[a] = 0; pd.C[a] = 0; pd.type[a] = 2; pd.blk_start[a] = blk;
        blk += (pd.count[a] + 255) / 256;
        pd.blk_start[NP] = blk;
        prep_kernel<<<blk, 256, 0, stream>>>(pd, wgt, imgT, flags);
    }

    ln12_kernel<<<5000, 256, 0, stream>>>(d_in[1], d_in[0], flags,
                                          wgt + W_LN1_G, wgt + W_LN1_B, ai);
    gemm_dual<512, 128, 64><<<dim3(313, 3), 256, 0, stream>>>(ai,
        wgt + W_TOFF_W, wgt + W_TOFF_B, T_RAD, toffB,
        wgt + W_TWT_W, wgt + W_TWT_B, twlB);
    temporal_kernel<<<1250, 256, 0, stream>>>(ai, toffB, twlB, d_in[3], d_in[5], flags, tfB);
    gemm_mfma<256, 256, 2><<<dim3(313, 4), 256, 0, stream>>>(tfB, wgt + W_TOUT_W, wgt + W_TOUT_B,
        x, d_in[0], nullptr, flags);
    ln_kernel<<<2500, 256, 0, stream>>>(x, wgt + W_LN2_G, wgt + W_LN2_B, q2B);
    gemm_dual<256, 256, 128><<<dim3(313, 6), 256, 0, stream>>>(q2B,
        wgt + W_SOFF_W, wgt + W_SOFF_B, S_RAD, soffB,
        wgt + W_SWT_W, wgt + W_SWT_B, swlB);
    spatial_kernel<<<2500, 256, 0, stream>>>(soffB, swlB, d_in[4], d_in[28], imgT, d_in[2],
                                             use_imgT, flags, sfB);
    gemm_mfma<256, 256, 3><<<dim3(313, 4), 256, 0, stream>>>(sfB, wgt + W_SOUT_W, wgt + W_SOUT_B,
        x, nullptr, x, flags);
    ffn_mfma<<<625, 256, 0, stream>>>(x, wgt + W_LN3_G, wgt + W_LN3_B,
                                      wgt + W_FFN_W1, wgt + W_FFN_B1,
                                      wgt + W_FFN_W2, wgt + W_FFN_B2, d_out, flags);
}

// Round 12
// 475.303 us; speedup vs baseline: 1.1413x; 1.1311x over previous
//
#include <hip/hip_runtime.h>
#include <hip/hip_bf16.h>
#include <hip/hip_fp16.h>

#define N_Q 10000
#define D_MODEL 256
#define NH 8
#define PT 4
#define PP 4
#define PS 4
#define DFF 1024
#define NC 6
#define HF 24
#define WF 60
#define BH 100
#define BW 100
#define T_RAD 0.15f
#define S_RAD 0.12f

typedef __hip_bfloat16 bf16;
typedef __attribute__((ext_vector_type(8))) short short8;
typedef __attribute__((ext_vector_type(4))) float f32x4;

__device__ __forceinline__ float b2f(bf16 v) { return __bfloat162float(v); }
__device__ __forceinline__ bf16 f2b(float v) { return __float2bfloat16(v); }

__device__ __forceinline__ f32x4 mfma16(short8 a, short8 b, f32x4 c) {
    return __builtin_amdgcn_mfma_f32_16x16x32_bf16(a, b, c, 0, 0, 0);
}

// dtype-adaptive loads/stores; f: 0=f32, 1=bf16, 2=f16
__device__ __forceinline__ float load_any(const void* p, long i, int f) {
    if (f == 0) return ((const float*)p)[i];
    if (f == 1) return b2f(((const bf16*)p)[i]);
    return __half2float(((const __half*)p)[i]);
}
__device__ __forceinline__ void store_any(void* p, long i, int f, float v) {
    if (f == 0)      ((float*)p)[i] = v;
    else if (f == 1) ((bf16*)p)[i] = f2b(v);
    else             ((__half*)p)[i] = __float2half(v);
}

__device__ __forceinline__ unsigned pack2(float a, float b) {
    bf16 x = f2b(a), y = f2b(b);
    unsigned short ux = *(unsigned short*)&x, uy = *(unsigned short*)&y;
    return (unsigned)ux | ((unsigned)uy << 16);
}

// ---------------- dtype / mask-width detection (parallel) ----------------
__global__ __launch_bounds__(256) void detect_kernel(const void* __restrict__ ln1g,
                                                     const void* __restrict__ mask,
                                                     int* __restrict__ flags) {
    __shared__ int sh[6];
    int tid = threadIdx.x;
    if (tid < 6) sh[tid] = (tid == 0 || tid == 2 || tid == 4) ? 1 : 0;
    __syncthreads();
    const unsigned long long* m64 = (const unsigned long long*)mask;
    const unsigned int*       m32 = (const unsigned int*)mask;
    const unsigned short*     m16 = (const unsigned short*)mask;
    int lok8 = 1, lones8 = 0, lok4 = 1, lones4 = 0, lok2 = 1, lones2 = 0;
    for (int i = tid; i < 480; i += 256) {
        if (i < 120) {
            unsigned long long v = m64[i];
            if (v == 1ULL) lones8++; else if (v != 0ULL) lok8 = 0;
        }
        if (i < 240) {
            unsigned int v = m32[i];
            if (v == 1u || v == 0x3F800000u) lones4++; else if (v != 0u) lok4 = 0;
        }
        unsigned short v = m16[i];
        if (v == 1 || v == 0x3F80) lones2++; else if (v != 0) lok2 = 0;
    }
    atomicAnd(&sh[0], lok8); atomicAdd(&sh[1], lones8);
    atomicAnd(&sh[2], lok4); atomicAdd(&sh[3], lones4);
    atomicAnd(&sh[4], lok2); atomicAdd(&sh[5], lones2);
    __syncthreads();
    if (tid == 0) {
        unsigned short u0 = ((const unsigned short*)ln1g)[0];
        flags[0] = (u0 == 0x3F80) ? 1 : (u0 == 0x3C00 ? 2 : 0);
        int ms;
        if (sh[0] && sh[1] > 30)       ms = 8;
        else if (sh[2] && sh[3] > 60)  ms = 4;
        else if (sh[4] && sh[5] > 120) ms = 2;
        else                           ms = 1;
        flags[1] = ms;
    }
}

// ---------------- unified weight/image prep: transposes + flat cvt + img transpose ----------------
#define NP 23
struct PrepDesc {
    const void* src[NP];
    int dst_off[NP];
    int count[NP];
    int R[NP];
    int C[NP];
    int type[NP];       // 0 flat cvt, 1 transpose, 2 img transpose
    int blk_start[NP + 1];
};
__global__ __launch_bounds__(256) void prep_kernel(PrepDesc pd, bf16* __restrict__ wgt,
                                                   bf16* __restrict__ imgT,
                                                   const int* __restrict__ flags) {
    int blk = blockIdx.x;
    int a = 0;
    while (a < NP - 1 && blk >= pd.blk_start[a + 1]) a++;
    int i = (blk - pd.blk_start[a]) * 256 + threadIdx.x;
    if (i >= pd.count[a]) return;
    int f = flags[0];
    int ty = pd.type[a];
    if (ty == 0) {
        wgt[pd.dst_off[a] + i] = f2b(load_any(pd.src[a], i, f));
    } else if (ty == 1) {
        int R = pd.R[a], C = pd.C[a];
        int c = i / R, r = i % R;
        wgt[pd.dst_off[a] + i] = f2b(load_any(pd.src[a], (long)r * C + c, f));
    } else {
        int ch = i & 255;
        int t = i >> 8;
        int xx = t % WF; t /= WF;
        int yy = t % HF;
        int c  = t / HF;
        long src = (((long)(c * 256) + ch) * HF + yy) * WF + xx;
        imgT[i] = f2b(load_any(pd.src[a], src, f));
    }
}

// ---------------- LN1 over prev_bev & query, wave-per-row -> ai[N,512] ----------------
__global__ __launch_bounds__(256) void ln12_kernel(const void* __restrict__ pb,
                                                   const void* __restrict__ q,
                                                   const int* __restrict__ flags,
                                                   const bf16* __restrict__ g,
                                                   const bf16* __restrict__ b,
                                                   bf16* __restrict__ out) {
    int wv = threadIdx.x >> 6, lane = threadIdx.x & 63;
    long row = (long)blockIdx.x * 4 + wv;
    const void* src; long r; int ooff;
    if (row < N_Q) { src = pb; r = row; ooff = 0; }
    else           { src = q;  r = row - N_Q; ooff = 256; }
    int f = flags[0];
    float v0, v1, v2, v3;
    if (f == 0) {
        float4 t = ((const float4*)src)[r * 64 + lane];
        v0 = t.x; v1 = t.y; v2 = t.z; v3 = t.w;
    } else {
        uint2 t = ((const uint2*)src)[r * 64 + lane];
        if (f == 1) {
            v0 = __uint_as_float(t.x << 16); v1 = __uint_as_float(t.x & 0xFFFF0000u);
            v2 = __uint_as_float(t.y << 16); v3 = __uint_as_float(t.y & 0xFFFF0000u);
        } else {
            __half2 h0 = *(__half2*)&t.x, h1 = *(__half2*)&t.y;
            v0 = __half2float(h0.x); v1 = __half2float(h0.y);
            v2 = __half2float(h1.x); v3 = __half2float(h1.y);
        }
    }
    float s1 = v0 + v1 + v2 + v3;
    float s2 = v0 * v0 + v1 * v1 + v2 * v2 + v3 * v3;
    #pragma unroll
    for (int m = 32; m > 0; m >>= 1) {
        s1 += __shfl_xor(s1, m);
        s2 += __shfl_xor(s2, m);
    }
    float mu = s1 * (1.f / 256.f);
    float var = s2 * (1.f / 256.f) - mu * mu;
    float inv = rsqrtf(var + 1e-5f);
    int k = lane * 4;
    float o0 = (v0 - mu) * inv * b2f(g[k+0]) + b2f(b[k+0]);
    float o1 = (v1 - mu) * inv * b2f(g[k+1]) + b2f(b[k+1]);
    float o2 = (v2 - mu) * inv * b2f(g[k+2]) + b2f(b[k+2]);
    float o3 = (v3 - mu) * inv * b2f(g[k+3]) + b2f(b[k+3]);
    uint2 st = {pack2(o0, o1), pack2(o2, o3)};
    *reinterpret_cast<uint2*>(out + r * 512 + ooff + k) = st;
}

// ---------------- LayerNorm (f32 in), wave-per-row -> bf16 out ----------------
__global__ __launch_bounds__(256) void ln_kernel(const float* __restrict__ in,
                                                 const bf16* __restrict__ g,
                                                 const bf16* __restrict__ b,
                                                 bf16* __restrict__ out) {
    int wv = threadIdx.x >> 6, lane = threadIdx.x & 63;
    long r = (long)blockIdx.x * 4 + wv;
    float4 t = ((const float4*)in)[r * 64 + lane];
    float s1 = t.x + t.y + t.z + t.w;
    float s2 = t.x * t.x + t.y * t.y + t.z * t.z + t.w * t.w;
    #pragma unroll
    for (int m = 32; m > 0; m >>= 1) {
        s1 += __shfl_xor(s1, m);
        s2 += __shfl_xor(s2, m);
    }
    float mu = s1 * (1.f / 256.f);
    float var = s2 * (1.f / 256.f) - mu * mu;
    float inv = rsqrtf(var + 1e-5f);
    int k = lane * 4;
    float o0 = (t.x - mu) * inv * b2f(g[k+0]) + b2f(b[k+0]);
    float o1 = (t.y - mu) * inv * b2f(g[k+1]) + b2f(b[k+1]);
    float o2 = (t.z - mu) * inv * b2f(g[k+2]) + b2f(b[k+2]);
    float o3 = (t.w - mu) * inv * b2f(g[k+3]) + b2f(b[k+3]);
    uint2 st = {pack2(o0, o1), pack2(o2, o3)};
    *reinterpret_cast<uint2*>(out + r * 256 + k) = st;
}

// ---------------- MFMA GEMM: out[M,J] = A @ WT^T + bias; cols split by blockIdx.y ----------------
template <int K, int J, int MODE>
__global__ __launch_bounds__(256) void gemm_mfma(const bf16* __restrict__ A,
                                                 const bf16* __restrict__ WT,
                                                 const bf16* __restrict__ bias,
                                                 float* __restrict__ outf,
                                                 const void* __restrict__ resraw,
                                                 const float* __restrict__ resf,
                                                 const int* __restrict__ flags) {
    constexpr int LDK = K + 8;
    __shared__ bf16 As[32 * LDK];
    int tid = threadIdx.x;
    int row0 = blockIdx.x * 32;
    int col0 = blockIdx.y * 64;
    for (int t = tid; t < 32 * (K / 8); t += 256) {
        int r = t / (K / 8), kq = t % (K / 8);
        uint4 u = {0u, 0u, 0u, 0u};
        if (row0 + r < N_Q)
            u = *reinterpret_cast<const uint4*>(A + (size_t)(row0 + r) * K + kq * 8);
        *reinterpret_cast<uint4*>(&As[r * LDK + kq * 8]) = u;
    }
    __syncthreads();
    int wave = tid >> 6, lane = tid & 63;
    int l = lane & 15, quad = lane >> 4;
    int rh = wave >> 1, ch = wave & 1;
    constexpr int NK = K / 32;
    short8 afr[NK];
    const bf16* arow = &As[(rh * 16 + l) * LDK + quad * 8];
    #pragma unroll
    for (int ks = 0; ks < NK; ks++)
        afr[ks] = *reinterpret_cast<const short8*>(arow + ks * 32);
    int fdt = flags[0];
    #pragma unroll
    for (int ct = 0; ct < 2; ct++) {
        int col = col0 + ch * 32 + ct * 16 + l;
        const bf16* wrow = WT + (size_t)col * K + quad * 8;
        f32x4 acc = {0.f, 0.f, 0.f, 0.f};
        #pragma unroll
        for (int ks = 0; ks < NK; ks++) {
            short8 bfr = *reinterpret_cast<const short8*>(wrow + ks * 32);
            acc = mfma16(afr[ks], bfr, acc);
        }
        float bb = b2f(bias[col]);
        #pragma unroll
        for (int r = 0; r < 4; r++) {
            int row = row0 + rh * 16 + quad * 4 + r;
            if (row >= N_Q) continue;
            long o = (long)row * J + col;
            float v = acc[r] + bb;
            if (MODE == 2) outf[o] = v + load_any(resraw, o, fdt);
            else           outf[o] = v + resf[o];
        }
    }
}

// ---------------- Dual MFMA GEMM (concat cols J1|J2); out1=tanh*scale bf16, out2 plain bf16 ----
template <int K, int J1, int J2>
__global__ __launch_bounds__(256) void gemm_dual(const bf16* __restrict__ A,
                                                 const bf16* __restrict__ WT1,
                                                 const bf16* __restrict__ b1, float scale,
                                                 bf16* __restrict__ out1,
                                                 const bf16* __restrict__ WT2,
                                                 const bf16* __restrict__ b2,
                                                 bf16* __restrict__ out2) {
    constexpr int LDK = K + 8;
    __shared__ bf16 As[32 * LDK];
    int tid = threadIdx.x;
    int row0 = blockIdx.x * 32;
    int col0 = blockIdx.y * 64;
    for (int t = tid; t < 32 * (K / 8); t += 256) {
        int r = t / (K / 8), kq = t % (K / 8);
        uint4 u = {0u, 0u, 0u, 0u};
        if (row0 + r < N_Q)
            u = *reinterpret_cast<const uint4*>(A + (size_t)(row0 + r) * K + kq * 8);
        *reinterpret_cast<uint4*>(&As[r * LDK + kq * 8]) = u;
    }
    __syncthreads();
    int wave = tid >> 6, lane = tid & 63;
    int l = lane & 15, quad = lane >> 4;
    int rh = wave >> 1, ch = wave & 1;
    constexpr int NK = K / 32;
    short8 afr[NK];
    const bf16* arow = &As[(rh * 16 + l) * LDK + quad * 8];
    #pragma unroll
    for (int ks = 0; ks < NK; ks++)
        afr[ks] = *reinterpret_cast<const short8*>(arow + ks * 32);
    #pragma unroll
    for (int ct = 0; ct < 2; ct++) {
        int jg = col0 + ch * 32 + ct * 16 + l;
        int in1 = jg < J1;
        int cl = in1 ? jg : jg - J1;
        const bf16* wrow = (in1 ? WT1 : WT2) + (size_t)cl * K + quad * 8;
        f32x4 acc = {0.f, 0.f, 0.f, 0.f};
        #pragma unroll
        for (int ks = 0; ks < NK; ks++) {
            short8 bfr = *reinterpret_cast<const short8*>(wrow + ks * 32);
            acc = mfma16(afr[ks], bfr, acc);
        }
        float bb = b2f(in1 ? b1[cl] : b2[cl]);
        #pragma unroll
        for (int r = 0; r < 4; r++) {
            int row = row0 + rh * 16 + quad * 4 + r;
            if (row >= N_Q) continue;
            float v = acc[r] + bb;
            if (in1) out1[(long)row * J1 + cl] = f2b(tanhf(v) * scale);
            else     out2[(long)row * J2 + cl] = f2b(v);
        }
    }
}

// ---------------- Fused MFMA FFN: LN3 -> @w1T,relu -> @w2T -> +x -> out ----------------
__global__ __launch_bounds__(256) void ffn_mfma(const float* __restrict__ x,
                                                const bf16* __restrict__ g3,
                                                const bf16* __restrict__ b3,
                                                const bf16* __restrict__ w1T,
                                                const bf16* __restrict__ b1,
                                                const bf16* __restrict__ w2T,
                                                const bf16* __restrict__ b2v,
                                                void* __restrict__ out,
                                                const int* __restrict__ flags) {
    constexpr int LDH = DFF + 8;
    constexpr int LDX = D_MODEL + 8;
    __shared__ bf16 hbuf[16 * LDH];
    bf16* xl = hbuf;
    int tid = threadIdx.x;
    int row0 = blockIdx.x * 16;
    {
        int r = tid >> 4, lr = tid & 15;
        const float* xr = x + (long)(row0 + r) * 256 + lr * 16;
        float vals[16];
        float s1 = 0.f, s2 = 0.f;
        #pragma unroll
        for (int i = 0; i < 16; i++) {
            float v = xr[i];
            vals[i] = v; s1 += v; s2 += v * v;
        }
        #pragma unroll
        for (int off = 8; off > 0; off >>= 1) {
            s1 += __shfl_down(s1, off, 16);
            s2 += __shfl_down(s2, off, 16);
        }
        s1 = __shfl(s1, 0, 16);
        s2 = __shfl(s2, 0, 16);
        float mu = s1 * (1.f / 256.f);
        float var = s2 * (1.f / 256.f) - mu * mu;
        float inv = rsqrtf(var + 1e-5f);
        #pragma unroll
        for (int i = 0; i < 16; i++) {
            int k = lr * 16 + i;
            xl[r * LDX + k] = f2b((vals[i] - mu) * inv * b2f(g3[k]) + b2f(b3[k]));
        }
    }
    __syncthreads();
    int wave = tid >> 6, lane = tid & 63;
    int l = lane & 15, quad = lane >> 4;
    short8 afr[8];
    {
        const bf16* arow = xl + l * LDX + quad * 8;
        #pragma unroll
        for (int ks = 0; ks < 8; ks++)
            afr[ks] = *reinterpret_cast<const short8*>(arow + ks * 32);
    }
    __syncthreads();
    for (int ct = 0; ct < 16; ct++) {
        int col = wave * 256 + ct * 16 + l;
        const bf16* wrow = w1T + (size_t)col * 256 + quad * 8;
        f32x4 acc = {0.f, 0.f, 0.f, 0.f};
        #pragma unroll
        for (int ks = 0; ks < 8; ks++) {
            short8 bfr = *reinterpret_cast<const short8*>(wrow + ks * 32);
            acc = mfma16(afr[ks], bfr, acc);
        }
        float bb = b2f(b1[col]);
        #pragma unroll
        for (int r = 0; r < 4; r++)
            hbuf[(quad * 4 + r) * LDH + col] = f2b(fmaxf(acc[r] + bb, 0.f));
    }
    __syncthreads();
    int fdt = flags[0];
    for (int ct = 0; ct < 4; ct++) {
        int col = wave * 64 + ct * 16 + l;
        const bf16* wrow = w2T + (size_t)col * 1024 + quad * 8;
        const bf16* hrow = hbuf + l * LDH + quad * 8;
        f32x4 acc = {0.f, 0.f, 0.f, 0.f};
        #pragma unroll 8
        for (int ks = 0; ks < 32; ks++) {
            short8 a2 = *reinterpret_cast<const short8*>(hrow + ks * 32);
            short8 bfr = *reinterpret_cast<const short8*>(wrow + ks * 32);
            acc = mfma16(a2, bfr, acc);
        }
        float bb = b2f(b2v[col]);
        #pragma unroll
        for (int r = 0; r < 4; r++) {
            long o = (long)(row0 + quad * 4 + r) * 256 + col;
            store_any(out, o, fdt, x[o] + acc[r] + bb);
        }
    }
}

// ---------------- Temporal sampling (8 q/block, 8 ch/thread, conditional corners) ----------------
__global__ __launch_bounds__(256) void temporal_kernel(const bf16* __restrict__ ai,
                                                       const bf16* __restrict__ toffB,
                                                       const bf16* __restrict__ twlB,
                                                       const void* __restrict__ ref2d,
                                                       const void* __restrict__ ego,
                                                       const int* __restrict__ flags,
                                                       bf16* __restrict__ tfB) {
    int tid = threadIdx.x;
    int ql = tid >> 5, t = tid & 31;
    int g = t >> 2, q4 = t & 3;
    long n0 = (long)blockIdx.x * 8;
    __shared__ float s_toff[8][8][17];
    __shared__ float s_twl[8][64];
    __shared__ float s_base[8][4];
    for (int i = tid; i < 8 * 128; i += 256) {
        int q = i >> 7, j = i & 127;
        int si = j >> 6, r = j & 63, gg = r >> 3, w = r & 7;
        s_toff[q][gg][si * 8 + w] = b2f(toffB[n0 * 128 + i]);
    }
    for (int i = tid; i < 8 * 64; i += 256) s_twl[i >> 6][i & 63] = b2f(twlB[n0 * 64 + i]);
    if (tid < 8) {
        int f = flags[0];
        float rx = load_any(ref2d, (n0 + tid) * 2, f), ry = load_any(ref2d, (n0 + tid) * 2 + 1, f);
        s_base[tid][0] = rx + load_any(ego, 0, f); s_base[tid][1] = ry + load_any(ego, 1, f);
        s_base[tid][2] = rx;                       s_base[tid][3] = ry;
    }
    __syncthreads();
    float acc[8];
    #pragma unroll
    for (int i = 0; i < 8; i++) acc[i] = 0.f;
    int choff = g * 32 + q4 * 8;
    #pragma unroll
    for (int si = 0; si < 2; si++) {
        float l0 = s_twl[ql][si * 32 + g * 4 + 0], l1 = s_twl[ql][si * 32 + g * 4 + 1];
        float l2 = s_twl[ql][si * 32 + g * 4 + 2], l3 = s_twl[ql][si * 32 + g * 4 + 3];
        float mx = fmaxf(fmaxf(l0, l1), fmaxf(l2, l3));
        float e0 = __expf(l0 - mx), e1 = __expf(l1 - mx);
        float e2 = __expf(l2 - mx), e3 = __expf(l3 - mx);
        float inv = 1.f / (e0 + e1 + e2 + e3);
        float wts[4] = {e0 * inv, e1 * inv, e2 * inv, e3 * inv};
        int aoff = si * 256;
        float bx = s_base[ql][si * 2], by = s_base[ql][si * 2 + 1];
        #pragma unroll
        for (int pt = 0; pt < 4; pt++) {
            float u = bx + s_toff[ql][g][si * 8 + pt * 2 + 0];
            float v = by + s_toff[ql][g][si * 8 + pt * 2 + 1];
            float ix = u * (float)BW - 0.5f;
            float iy = v * (float)BH - 0.5f;
            float x0f = floorf(ix), y0f = floorf(iy);
            int x0 = (int)x0f, y0 = (int)y0f;
            float wx1 = ix - x0f, wy1 = iy - y0f;
            float wx0 = 1.f - wx1, wy0 = 1.f - wy1;
            #pragma unroll
            for (int cy = 0; cy < 2; cy++) {
                int yy = y0 + cy;
                if ((unsigned)yy >= BH) continue;
                float wy = cy ? wy1 : wy0;
                #pragma unroll
                for (int cx = 0; cx < 2; cx++) {
                    int xx = x0 + cx;
                    if ((unsigned)xx >= BW) continue;
                    float wq = wts[pt] * wy * (cx ? wx1 : wx0);
                    uint4 uu = *reinterpret_cast<const uint4*>(
                        ai + (long)(yy * BW + xx) * 512 + aoff + choff);
                    acc[0] += wq * __uint_as_float(uu.x << 16);
                    acc[1] += wq * __uint_as_float(uu.x & 0xFFFF0000u);
                    acc[2] += wq * __uint_as_float(uu.y << 16);
                    acc[3] += wq * __uint_as_float(uu.y & 0xFFFF0000u);
                    acc[4] += wq * __uint_as_float(uu.z << 16);
                    acc[5] += wq * __uint_as_float(uu.z & 0xFFFF0000u);
                    acc[6] += wq * __uint_as_float(uu.w << 16);
                    acc[7] += wq * __uint_as_float(uu.w & 0xFFFF0000u);
                }
            }
        }
    }
    uint4 o;
    o.x = pack2(acc[0] * 0.5f, acc[1] * 0.5f);
    o.y = pack2(acc[2] * 0.5f, acc[3] * 0.5f);
    o.z = pack2(acc[4] * 0.5f, acc[5] * 0.5f);
    o.w = pack2(acc[6] * 0.5f, acc[7] * 0.5f);
    *reinterpret_cast<uint4*>(tfB + (n0 + ql) * 256 + choff) = o;
}

// ---------------- Spatial v8: wave-per-query, corner-paired half-waves, 8 ch/lane ----------------
// 256 thr = 4 waves = 4 queries. lane: cxh = lane>>5 (corner-x half), h5 = lane&31,
// g = h5>>2 (head), c8 = h5&3 (channel chunk of 8). One load instruction covers the two
// adjacent corner rows (contiguous 1024 B) -> instruction-level footprint pairing.
__global__ __launch_bounds__(256) void spatial_kernel(const bf16* __restrict__ soffB,
                                                      const bf16* __restrict__ swlB,
                                                      const void* __restrict__ refcam,
                                                      const void* __restrict__ bmask,
                                                      const bf16* __restrict__ imgT,
                                                      const void* __restrict__ img_raw,
                                                      int use_imgT,
                                                      const int* __restrict__ flags,
                                                      bf16* __restrict__ sfB) {
    int tid = threadIdx.x;
    int ql = tid >> 6, lane = tid & 63;
    int cxh = lane >> 5;
    int h5 = lane & 31;
    int g = h5 >> 2, c8 = h5 & 3;
    long n0 = (long)blockIdx.x * 4;
    __shared__ float s_soff[4][8][33];
    __shared__ float s_swl[4][144];        // [q][j*9 + g]
    __shared__ float s_ref[4][NC][PP][2];
    __shared__ int   s_vis[4][NC][PP];
    for (int i = tid; i < 4 * 256; i += 256) {
        int q = i >> 8, j = i & 255;
        s_soff[q][j >> 5][j & 31] = b2f(soffB[n0 * 256 + i]);
    }
    for (int i = tid; i < 4 * 128; i += 256) {
        int q = i >> 7, jr = i & 127;
        int gg = jr >> 4, j = jr & 15;
        s_swl[q][j * 9 + gg] = b2f(swlB[n0 * 128 + i]);
    }
    int fdt = flags[0], msz = flags[1];
    if (tid < 4 * 48) {
        int q = tid / 48, r = tid % 48;
        s_ref[q][r >> 3][(r & 7) >> 1][r & 1] =
            load_any(refcam, ((long)(r >> 3) * N_Q + n0 + q) * 8 + (r & 7), fdt);
    }
    // s_vis staging: 96 entries, window [160, 256)
    if (tid >= 160 && tid < 160 + 4 * 24) {
        int tt = tid - 160;
        int q = tt / 24, r = tt % 24; int c = r >> 2, p = r & 3;
        long idx = ((long)c * N_Q + n0 + q) * 4 + p;
        int v;
        if (msz == 1)      v = ((const unsigned char*)bmask)[idx] != 0;
        else if (msz == 2) v = ((const unsigned short*)bmask)[idx] != 0;
        else if (msz == 4) v = ((const unsigned int*)bmask)[idx] != 0u;
        else               v = ((const unsigned long long*)bmask)[idx] != 0ULL;
        s_vis[q][c][p] = v;
    }
    __syncthreads();
    // hoisted softmax numerators (shift-invariant masked softmax)
    float ew[16];
    {
        float lw[16], mx = -3e38f;
        #pragma unroll
        for (int j = 0; j < 16; j++) { lw[j] = s_swl[ql][j * 9 + g]; mx = fmaxf(mx, lw[j]); }
        #pragma unroll
        for (int j = 0; j < 16; j++) ew[j] = __expf(lw[j] - mx);
    }
    float acc[8];
    #pragma unroll
    for (int i = 0; i < 8; i++) acc[i] = 0.f;
    float cnt = 0.f;
    int choff = g * 32 + c8 * 8;
    for (int c = 0; c < NC; c++) {
        int m0 = s_vis[ql][c][0], m1 = s_vis[ql][c][1];
        int m2 = s_vis[ql][c][2], m3 = s_vis[ql][c][3];
        if (!(m0 | m1 | m2 | m3)) continue;
        cnt += 1.f;
        float sum = 0.f;
        #pragma unroll
        for (int j = 0; j < 16; j++)
            sum += s_vis[ql][c][j >> 2] ? ew[j] : 0.f;
        float inv = 1.f / fmaxf(sum, 1e-20f);
        const bf16* img = imgT + (long)c * HF * WF * 256 + choff;
        #pragma unroll
        for (int p = 0; p < PP; p++) {
            if (!s_vis[ql][c][p]) continue;
            float rx = s_ref[ql][c][p][0], ry = s_ref[ql][c][p][1];
            #pragma unroll
            for (int s = 0; s < PS; s++) {
                float wi = ew[p * 4 + s] * inv;
                float u = rx + s_soff[ql][g][p * 8 + s * 2 + 0];
                float v = ry + s_soff[ql][g][p * 8 + s * 2 + 1];
                float ix = u * (float)WF - 0.5f, iy = v * (float)HF - 0.5f;
                float x0f = floorf(ix), y0f = floorf(iy);
                int x0 = (int)x0f, y0 = (int)y0f;
                float wx1 = ix - x0f, wy1 = iy - y0f;
                // this half-wave's corner-x: validity in weight, address clamped
                // (clamped OOB address == partner corner's row -> no extra lines)
                int xi = x0 + cxh;
                float wx = cxh ? wx1 : (1.f - wx1);
                wx *= ((unsigned)xi < WF) ? 1.f : 0.f;
                int xcl = min(max(xi, 0), WF - 1);
                float wiwx = wi * wx;
                #pragma unroll
                for (int cy = 0; cy < 2; cy++) {
                    int yy = y0 + cy;
                    if ((unsigned)yy >= HF) continue;   // wave-uniform branch
                    float wq = wiwx * (cy ? wy1 : (1.f - wy1));
                    if (use_imgT) {
                        uint4 uu = *reinterpret_cast<const uint4*>(
                            img + (long)(yy * WF + xcl) * 256);
                        acc[0] += wq * __uint_as_float(uu.x << 16);
                        acc[1] += wq * __uint_as_float(uu.x & 0xFFFF0000u);
                        acc[2] += wq * __uint_as_float(uu.y << 16);
                        acc[3] += wq * __uint_as_float(uu.y & 0xFFFF0000u);
                        acc[4] += wq * __uint_as_float(uu.z << 16);
                        acc[5] += wq * __uint_as_float(uu.z & 0xFFFF0000u);
                        acc[6] += wq * __uint_as_float(uu.w << 16);
                        acc[7] += wq * __uint_as_float(uu.w & 0xFFFF0000u);
                    } else {
                        #pragma unroll
                        for (int e = 0; e < 8; e++)
                            acc[e] += wq * load_any(img_raw,
                                (((long)c * 256 + choff + e) * HF + yy) * WF + xcl, fdt);
                    }
                }
            }
        }
    }
    // combine the two corner-x halves: lane i and lane i^32 hold same channels
    #pragma unroll
    for (int e = 0; e < 8; e++) acc[e] += __shfl_xor(acc[e], 32);
    float invc = 1.f / fmaxf(cnt, 1.f);
    if (cxh == 0) {
        uint4 o;
        o.x = pack2(acc[0] * invc, acc[1] * invc);
        o.y = pack2(acc[2] * invc, acc[3] * invc);
        o.z = pack2(acc[4] * invc, acc[5] * invc);
        o.w = pack2(acc[6] * invc, acc[7] * invc);
        *reinterpret_cast<uint4*>(sfB + (n0 + ql) * 256 + choff) = o;
    }
}

// bf16 element offsets inside the weight region (matrices stored TRANSPOSED [J][K])
#define W_TOFF_W 0
#define W_TOFF_B 65536
#define W_TWT_W  65664
#define W_TWT_B  98432
#define W_TOUT_W 98496
#define W_TOUT_B 164032
#define W_SOFF_W 164288
#define W_SOFF_B 229824
#define W_SWT_W  230080
#define W_SWT_B  262848
#define W_SOUT_W 262976
#define W_SOUT_B 328512
#define W_FFN_W1 328768
#define W_FFN_B1 590912
#define W_FFN_W2 591936
#define W_FFN_B2 854080
#define W_LN1_G  854336
#define W_LN1_B  854592
#define W_LN2_G  854848
#define W_LN2_B  855104
#define W_LN3_G  855360
#define W_LN3_B  855616

// byte offsets in workspace (total ~35.6 MB)
#define OB_WGT   0
#define OB_FLAGS 1711744
#define OB_AI    1712640
#define OB_TF    11952640
#define OB_X     17072640
#define OB_T4    27312640
#define OB_IMG   31152640
#define WS_NEED_IMG 35576320ULL

extern "C" void kernel_launch(void* const* d_in, const int* in_sizes, int n_in,
                              void* d_out, int out_size, void* d_ws, size_t ws_size,
                              hipStream_t stream) {
    char* W8 = (char*)d_ws;
    bf16*  wgt   = (bf16*)(W8 + OB_WGT);
    int*   flags = (int*)(W8 + OB_FLAGS);
    bf16*  ai    = (bf16*)(W8 + OB_AI);                 // N x 512, pb | q1
    bf16*  q2B   = ai;                                  // N x 256 (after temporal)
    bf16*  sfB   = (bf16*)(W8 + OB_AI + 5120000);       // N x 256
    bf16*  tfB   = (bf16*)(W8 + OB_TF);                 // N x 256
    bf16*  soffB = tfB;                                 // N x 256 (after t_out gemm)
    float* x     = (float*)(W8 + OB_X);                 // N x 256 f32 trunk
    bf16*  toffB = (bf16*)(W8 + OB_T4);                 // N x 128
    bf16*  twlB  = (bf16*)(W8 + OB_T4 + 2560000);       // N x 64
    bf16*  swlB  = toffB;                               // N x 128 (after temporal)
    bf16*  imgT  = (bf16*)(W8 + OB_IMG);                // NC*HF*WF*256
    int use_imgT = (ws_size >= WS_NEED_IMG) ? 1 : 0;

    detect_kernel<<<1, 256, 0, stream>>>(d_in[22], d_in[28], flags);

    {   // unified prep: 8 transposes + 14 flat cvts + img transpose
        PrepDesc pd;
        const int tsrc[8] = {6, 8, 10, 12, 14, 16, 18, 20};
        const int toff[8] = {W_TOFF_W, W_TWT_W, W_TOUT_W, W_SOFF_W, W_SWT_W, W_SOUT_W,
                             W_FFN_W1, W_FFN_W2};
        const int tR[8] = {512, 512, 256, 256, 256, 256, 256, 1024};
        const int tC[8] = {128, 64, 256, 256, 128, 256, 1024, 256};
        const int fsrc[14] = {7, 9, 11, 13, 15, 17, 19, 21, 22, 23, 24, 25, 26, 27};
        const int foff[14] = {W_TOFF_B, W_TWT_B, W_TOUT_B, W_SOFF_B, W_SWT_B, W_SOUT_B,
                              W_FFN_B1, W_FFN_B2, W_LN1_G, W_LN1_B, W_LN2_G, W_LN2_B,
                              W_LN3_G, W_LN3_B};
        const int fcnt[14] = {128, 64, 256, 256, 128, 256, 1024, 256, 256, 256, 256, 256, 256, 256};
        int a = 0, blk = 0;
        for (int i = 0; i < 8; i++, a++) {
            pd.src[a] = d_in[tsrc[i]]; pd.dst_off[a] = toff[i];
            pd.count[a] = tR[i] * tC[i]; pd.R[a] = tR[i]; pd.C[a] = tC[i];
            pd.type[a] = 1; pd.blk_start[a] = blk; blk += (pd.count[a] + 255) / 256;
        }
        for (int i = 0; i < 14; i++, a++) {
            pd.src[a] = d_in[fsrc[i]]; pd.dst_off[a] = foff[i];
            pd.count[a] = fcnt[i]; pd.R[a] = 0; pd.C[a] = 0;
            pd.type[a] = 0; pd.blk_start[a] = blk; blk += (pd.count[a] + 255) / 256;
        }
        pd.src[a] = d_in[2]; pd.dst_off[a] = 0;
        pd.count[a] = use_imgT ? NC * HF * WF * 256 : 0;
        pd.R[a] = 0; pd.C[a] = 0; pd.type[a] = 2; pd.blk_start[a] = blk;
        blk += (pd.count[a] + 255) / 256;
        pd.blk_start[NP] = blk;
        prep_kernel<<<blk, 256, 0, stream>>>(pd, wgt, imgT, flags);
    }

    ln12_kernel<<<5000, 256, 0, stream>>>(d_in[1], d_in[0], flags,
                                          wgt + W_LN1_G, wgt + W_LN1_B, ai);
    gemm_dual<512, 128, 64><<<dim3(313, 3), 256, 0, stream>>>(ai,
        wgt + W_TOFF_W, wgt + W_TOFF_B, T_RAD, toffB,
        wgt + W_TWT_W, wgt + W_TWT_B, twlB);
    temporal_kernel<<<1250, 256, 0, stream>>>(ai, toffB, twlB, d_in[3], d_in[5], flags, tfB);
    gemm_mfma<256, 256, 2><<<dim3(313, 4), 256, 0, stream>>>(tfB, wgt + W_TOUT_W, wgt + W_TOUT_B,
        x, d_in[0], nullptr, flags);
    ln_kernel<<<2500, 256, 0, stream>>>(x, wgt + W_LN2_G, wgt + W_LN2_B, q2B);
    gemm_dual<256, 256, 128><<<dim3(313, 6), 256, 0, stream>>>(q2B,
        wgt + W_SOFF_W, wgt + W_SOFF_B, S_RAD, soffB,
        wgt + W_SWT_W, wgt + W_SWT_B, swlB);
    spatial_kernel<<<2500, 256, 0, stream>>>(soffB, swlB, d_in[4], d_in[28], imgT, d_in[2],
                                             use_imgT, flags, sfB);
    gemm_mfma<256, 256, 3><<<dim3(313, 4), 256, 0, stream>>>(sfB, wgt + W_SOUT_W, wgt + W_SOUT_B,
        x, nullptr, x, flags);
    ffn_mfma<<<625, 256, 0, stream>>>(x, wgt + W_LN3_G, wgt + W_LN3_B,
                                      wgt + W_FFN_W1, wgt + W_FFN_B1,
                                      wgt + W_FFN_W2, wgt + W_FFN_B2, d_out, flags);
}